// Round 16
// baseline (205.652 us; speedup 1.0000x reference)
//
#include <hip/hip_runtime.h>
#include <hip/hip_fp8.h>
#include <cstddef>

#define PI_F 3.14159265358979323846f

#define NCH 256   // C
#define NB  32    // B
#define NF  544   // n*(n/2+1),  f = i*17 + j

#define ASCALE     65536.0f
#define INV_ASCALE (1.0f/65536.0f)

typedef short  bf16x8 __attribute__((ext_vector_type(8)));
typedef float  f32x4  __attribute__((ext_vector_type(4)));

// ---- workspace layout (bytes), single-chunk, fp8 A ----
#define SZ_AFRAG ((size_t)NF*8*16*1024)         // 71,303,168 (fp8 fragments; tmp aliases)
#define SZ_P8    ((size_t)NF*NB*NCH)            // 4,456,448  (fp8 plane)
#define SZ_PB    ((size_t)NF*NB*NCH*2)          // 8,912,896  (bf16 plane)
#define SZ_P32   ((size_t)NF*NB*NCH*4)          // 17,825,792 (fp32 plane)
#define OFF_AFRAG ((size_t)0)
#define OFF_Z8R  (OFF_AFRAG + SZ_AFRAG)
#define OFF_Z8I  (OFF_Z8R + SZ_P8)
#define OFF_Z32R (OFF_Z8I + SZ_P8)
#define OFF_Z32I (OFF_Z32R + SZ_P32)
#define OFF_WXHR (OFF_Z32I + SZ_P32)
#define OFF_WXHI (OFF_WXHR + SZ_PB)
#define OFF_HFRAG (OFF_WXHI + SZ_PB)
#define SZ_HFRAG ((size_t)8*16*1024)            // 131,072
#define OFF_RED  (OFF_HFRAG + SZ_HFRAG)
#define WS_NEED  (OFF_RED + (size_t)4096)       // ~134 MB

// 32-point twiddle tables: COS32[k]=cos(2pi k/32), SIN32[k]=sin(2pi k/32)
__device__ constexpr float COS32[32] = {
     1.0000000000f,  0.9807852804f,  0.9238795325f,  0.8314696123f,
     0.7071067812f,  0.5555702330f,  0.3826834324f,  0.1950903220f,
     0.0000000000f, -0.1950903220f, -0.3826834324f, -0.5555702330f,
    -0.7071067812f, -0.8314696123f, -0.9238795325f, -0.9807852804f,
    -1.0000000000f, -0.9807852804f, -0.9238795325f, -0.8314696123f,
    -0.7071067812f, -0.5555702330f, -0.3826834324f, -0.1950903220f,
    -0.0000000000f,  0.1950903220f,  0.3826834324f,  0.5555702330f,
     0.7071067812f,  0.8314696123f,  0.9238795325f,  0.9807852804f };
__device__ constexpr float SIN32[32] = {
     0.0000000000f,  0.1950903220f,  0.3826834324f,  0.5555702330f,
     0.7071067812f,  0.8314696123f,  0.9238795325f,  0.9807852804f,
     1.0000000000f,  0.9807852804f,  0.9238795325f,  0.8314696123f,
     0.7071067812f,  0.5555702330f,  0.3826834324f,  0.1950903220f,
     0.0000000000f, -0.1950903220f, -0.3826834324f, -0.5555702330f,
    -0.7071067812f, -0.8314696123f, -0.9238795325f, -0.9807852804f,
    -1.0000000000f, -0.9807852804f, -0.9238795325f, -0.8314696123f,
    -0.7071067812f, -0.5555702330f, -0.3826834324f, -0.1950903220f };

__device__ __forceinline__ unsigned short f2bf(float x) {
    unsigned int u = __float_as_uint(x);
    u += 0x7FFFu + ((u >> 16) & 1u);            // RNE
    return (unsigned short)(u >> 16);
}
__device__ __forceinline__ float bf2f(unsigned int h) {
    return __uint_as_float(h << 16);
}
__device__ __forceinline__ unsigned int pack2(float a, float b) {
    return (unsigned int)f2bf(a) | ((unsigned int)f2bf(b) << 16);
}
__device__ __forceinline__ unsigned char f2e4m3(float x) {
    __hip_fp8_e4m3 h(x);
    return (unsigned char)h.__x;
}
__device__ __forceinline__ float e4m3f(unsigned int b) {
    __hip_fp8_e4m3 h; h.__x = (__hip_fp8_storage_t)b;
    return (float)h;
}
__device__ __forceinline__ unsigned int pk4_e4m3(const float* v) {
    return (unsigned)f2e4m3(v[0]) | ((unsigned)f2e4m3(v[1]) << 8) |
           ((unsigned)f2e4m3(v[2]) << 16) | ((unsigned)f2e4m3(v[3]) << 24);
}

// ---------------- norm of wfft (closed form via Parseval) ----------------
__global__ void norm_part(const float* __restrict__ w, float* __restrict__ red) {
    int idx = blockIdx.x * 256 + threadIdx.x;
    const float* wp = w + (size_t)idx * 9;
    float s2 = 0.f, aa = 0.f, bb = 0.f;
#pragma unroll
    for (int u = 0; u < 3; u++) {
        float w0 = wp[u*3+0], w1 = wp[u*3+1], w2 = wp[u*3+2];
        s2 += w0*w0 + w1*w1 + w2*w2;
        float au = w0 + w1 + w2, bu = w0 - w1 + w2;
        aa += au*au; bb += bu*bu;
    }
    float p = 512.f*s2 + 16.f*(aa + bb);
    __shared__ float sm[256];
    sm[threadIdx.x] = p; __syncthreads();
    for (int s = 128; s > 0; s >>= 1) {
        if (threadIdx.x < s) sm[threadIdx.x] += sm[threadIdx.x + s];
        __syncthreads();
    }
    if (threadIdx.x == 0) red[blockIdx.x] = sm[0];
}

__global__ void norm_final(const float* __restrict__ red, const float* __restrict__ alpha,
                           float* __restrict__ sig) {
    __shared__ float sm[256];
    sm[threadIdx.x] = red[threadIdx.x]; __syncthreads();
    for (int s = 128; s > 0; s >>= 1) {
        if (threadIdx.x < s) sm[threadIdx.x] += sm[threadIdx.x + s];
        __syncthreads();
    }
    if (threadIdx.x == 0) sig[0] = alpha[0] / sqrtf(sm[0]);
}

// ---------------- H fragments (A-operand: m=o, k=c), bf16 ----------------
__global__ void hfrag_build(const float* __restrict__ H, unsigned short* __restrict__ Hfrag) {
    int kk = blockIdx.x, mt = blockIdx.y, lane = threadIdx.x;   // 64 threads
    int o = mt*16 + (lane & 15), c0 = kk*32 + (lane >> 4)*8;
    const float* hp = H + (size_t)o*NCH + c0;
    uint4 u;
    u.x = pack2(hp[0], hp[1]); u.y = pack2(hp[2], hp[3]);
    u.z = pack2(hp[4], hp[5]); u.w = pack2(hp[6], hp[7]);
    ((uint4*)Hfrag)[((size_t)kk*16 + mt)*64 + lane] = u;
}

// ---------------- rfft2: register-resident DFT, 8 tiles per 256-thread block ----------------
__global__ __launch_bounds__(256) void rfft2_reg(const float* __restrict__ x,
                                                 float2* __restrict__ tmp)
{
    __shared__ float2 T[8][544];       // [half][r*17+j], ~35 KB
    __shared__ float2 Z[8][544];       // output staging, ~35 KB
    __shared__ float wc[32], wsn[32];
    int t = threadIdx.x;
    int half = t >> 5, lane = t & 31;
    int cb = blockIdx.x * 8 + half;    // tile index in tmp order: cb = c*32 + b
    int c = cb >> 5, b = cb & 31;
    if (t < 32) { wc[t] = COS32[t]; wsn[t] = SIN32[t]; }
    float xr[32];
    const float* xp = x + ((size_t)(b * NCH + c)) * 1024 + lane * 32;
#pragma unroll
    for (int q = 0; q < 8; q++) {
        float4 v = *(const float4*)(xp + q*4);
        xr[q*4+0] = v.x; xr[q*4+1] = v.y; xr[q*4+2] = v.z; xr[q*4+3] = v.w;
    }
    float x0v = xr[0], x16v = xr[16];
    float es[15], os[15];
#pragma unroll
    for (int s = 1; s <= 15; s++) { es[s-1] = xr[s] + xr[32-s]; os[s-1] = xr[s] - xr[32-s]; }
#pragma unroll
    for (int j = 0; j < 17; j++) {
        float ax = x0v + ((j & 1) ? -x16v : x16v);
        float ay = 0.f;
#pragma unroll
        for (int s = 1; s <= 15; s++) {
            int m = (j * s) & 31;
            ax += es[s-1] * COS32[m];
            ay -= os[s-1] * SIN32[m];
        }
        T[half][lane*17 + j] = make_float2(ax, ay);
    }
    __syncthreads();
    float wr_[16], wi_[16];
#pragma unroll
    for (int r = 0; r < 16; r++) {
        int m = (lane * r) & 31;
        wr_[r] = wc[m]; wi_[r] = wsn[m];
    }
    float sgn = (lane & 1) ? -1.f : 1.f;    // (-1)^i
#pragma unroll
    for (int j = 0; j < 17; j++) {
        float ax = 0.f, ay = 0.f;
#pragma unroll
        for (int r = 0; r < 16; r++) {
            float2 t1 = T[half][r*17 + j];
            float2 t2 = T[half][(r+16)*17 + j];
            float ex = fmaf(sgn, t2.x, t1.x);
            float ey = fmaf(sgn, t2.y, t1.y);
            ax += ex * wr_[r] + ey * wi_[r];
            ay += ey * wr_[r] - ex * wi_[r];
        }
        Z[half][lane*17 + j] = make_float2(ax, ay);
    }
    __syncthreads();
    float2* outp = tmp + (size_t)blockIdx.x * 8 * 544;
    const float2* zf = (const float2*)Z;
#pragma unroll
    for (int u = 0; u < 17; u++)
        outp[u*256 + t] = zf[u*256 + t];
}

// ---------------- transpose tmp[cb][f] -> fp32 planes + fp8 planes [f][b][c] ----------------
__global__ __launch_bounds__(256) void transpose_z(const float2* __restrict__ tmp,
        float* __restrict__ z32r, float* __restrict__ z32i,
        unsigned char* __restrict__ z8r, unsigned char* __restrict__ z8i)
{
    __shared__ float2 tile[32][33];
    int ct = blockIdx.x, ft = blockIdx.y, b = blockIdx.z;
    int t = threadIdx.x;
#pragma unroll
    for (int it = 0; it < 4; it++) {
        int idx = t + it*256; int cl = idx >> 5, fl = idx & 31;
        tile[cl][fl] = tmp[((size_t)((ct*32 + cl)*32 + b))*544 + ft*32 + fl];
    }
    __syncthreads();
#pragma unroll
    for (int it = 0; it < 4; it++) {
        int idx = t + it*256; int fl = idx >> 5, cl = idx & 31;
        float2 v = tile[cl][fl];
        size_t zi_ = ((size_t)(ft*32 + fl)*NB + b)*NCH + ct*32 + cl;
        z32r[zi_] = v.x; z32i[zi_] = v.y;
        z8r[zi_] = f2e4m3(v.x); z8i[zi_] = f2e4m3(v.y);
    }
}

// ---------------- A-build, factorized + direct fragment writes ----------------
__global__ __launch_bounds__(256) void a_build_direct(const float* __restrict__ w,
        const float* __restrict__ sig, unsigned int* __restrict__ Afrag)
{
    int mt = blockIdx.x, kk = blockIdx.y, j = blockIdx.z;   // 16, 8, 17
    int t = threadIdx.x;
    int wv = t & 127;
    int c   = mt*16 + ((wv >> 1) & 15);
    int cp0 = kk*32 + (wv >> 5)*8 + (wv & 1)*4;
    bool isReal = (t < 128);
    float sS = sig[0] * ASCALE;
    float sgnS = isReal ? sS : -sS;
    f32x4 P1, P2, P3, P4, P5;
#pragma unroll
    for (int e = 0; e < 4; e++) {
        int cp = cp0 + e;
        const float* p1 = w + ((size_t)c*NCH + cp)*9;
        const float* p2 = w + ((size_t)cp*NCH + c)*9;
        float u_[9];
#pragma unroll
        for (int q = 0; q < 9; q++)
            u_[q] = isReal ? (p1[q] - p2[q]) : (p1[q] + p2[q]);
        if (isReal) {
            P1[e] = sgnS * u_[4];
            P2[e] = sgnS * (u_[3] + u_[5]);
            P3[e] = sgnS * (u_[1] + u_[7]);
            P4[e] = sgnS * (u_[0] + u_[2] + u_[6] + u_[8]);
            P5[e] = sgnS * ((u_[6] - u_[8]) - (u_[0] - u_[2]));
        } else {
            P1[e] = sgnS * (u_[3] - u_[5]);
            P2[e] = sgnS * ((u_[0] - u_[2]) + (u_[6] - u_[8]));
            P3[e] = sgnS * (u_[1] - u_[7]);
            P4[e] = sgnS * ((u_[0] + u_[2]) - (u_[6] + u_[8]));
            P5[e] = 0.f;
        }
    }
    float cps = COS32[j], sns = SIN32[j];
    f32x4 Aj, Bj, Cj;
    if (isReal) { Aj = P1 + cps*P2; Bj = P3 + cps*P4; Cj = sns*P5; }
    else        { Aj = sns*P1;      Bj = sns*P2;      Cj = P3 + cps*P4; }
    unsigned int* out = Afrag + ((size_t)j*128 + kk*16 + mt)*256 + t;
#pragma unroll
    for (int i = 0; i < 32; i++) {
        f32x4 v = Aj + COS32[i]*Bj + SIN32[i]*Cj;   // compile-time twiddles
        *out = (unsigned)f2e4m3(v[0]) | ((unsigned)f2e4m3(v[1]) << 8)
             | ((unsigned)f2e4m3(v[2]) << 16) | ((unsigned)f2e4m3(v[3]) << 24);
        out += (size_t)17*32768;   // fl = i*17 + j
    }
}

// ---------------- neum_fused: t = z - A z ; wx = z32 - 2 A t ; wxh = H wx ----------------
__global__ __launch_bounds__(512) void neum_fused(
    const unsigned char* __restrict__ Afrag,
    const unsigned short* __restrict__ Hfrag,
    const unsigned char* __restrict__ z8r, const unsigned char* __restrict__ z8i,
    const float* __restrict__ z32r, const float* __restrict__ z32i,
    unsigned short* __restrict__ wxhR, unsigned short* __restrict__ wxhI)
{
    __shared__ uint2 lz8[2][1024];   // 16 KB: fp8 z, then fp8 t (in-place)
    __shared__ uint4 lw[2][1024];    // 32 KB: bf16 wx
    int fl = blockIdx.x;
    int f = fl;
    int t = threadIdx.x;
    const uint2* s0 = (const uint2*)(z8r + (size_t)f*8192);
    const uint2* s1 = (const uint2*)(z8i + (size_t)f*8192);
    for (int u = t; u < 2048; u += 512) {
        int p = u >> 10, idx = u & 1023;
        int b = idx >> 5, o16 = idx & 31;
        lz8[p][b*32 + (o16 ^ (b & 7))] = (p ? s1 : s0)[idx];
    }
    int w = t >> 6, lane = t & 63, lo = lane & 15, hi = lane >> 4;
    const uint2* A8 = (const uint2*)Afrag;
    const uint4* H4 = (const uint4*)Hfrag;
    long arK[8][2], aiK[8][2];
#pragma unroll
    for (int kk = 0; kk < 8; kk++) {
#pragma unroll
        for (int mt = 0; mt < 2; mt++) {
            int mtg = w*2 + mt;
            size_t idx = (((size_t)fl*8 + kk)*16 + mtg)*128 + lane;
            arK[kk][mt] = __builtin_bit_cast(long, A8[idx]);
            aiK[kk][mt] = __builtin_bit_cast(long, A8[idx + 64]);
        }
    }
    __syncthreads();
    f32x4 accr[2][2], acci[2][2];
    f32x4 zz = {0.f, 0.f, 0.f, 0.f};
#pragma unroll
    for (int mt = 0; mt < 2; mt++)
#pragma unroll
        for (int nt = 0; nt < 2; nt++) { accr[mt][nt] = zz; acci[mt][nt] = zz; }
    // ---- matmul 1: acc = A * z (fp8) ----
#pragma unroll
    for (int kk = 0; kk < 8; kk++) {
        long zr[2], zi_[2];
#pragma unroll
        for (int nt = 0; nt < 2; nt++) {
            int b = nt*16 + lo;
            int du = b*32 + ((kk*4 + hi) ^ (b & 7));
            zr[nt]  = __builtin_bit_cast(long, lz8[0][du]);
            zi_[nt] = __builtin_bit_cast(long, lz8[1][du]);
        }
#pragma unroll
        for (int mt = 0; mt < 2; mt++) {
            uint2 vb = __builtin_bit_cast(uint2, aiK[kk][mt]);
            long ain = __builtin_bit_cast(long, make_uint2(vb.x ^ 0x80808080u, vb.y ^ 0x80808080u));
#pragma unroll
            for (int nt = 0; nt < 2; nt++) {
                accr[mt][nt] = __builtin_amdgcn_mfma_f32_16x16x32_fp8_fp8(arK[kk][mt], zr[nt],  accr[mt][nt], 0, 0, 0);
                accr[mt][nt] = __builtin_amdgcn_mfma_f32_16x16x32_fp8_fp8(ain,        zi_[nt], accr[mt][nt], 0, 0, 0);
                acci[mt][nt] = __builtin_amdgcn_mfma_f32_16x16x32_fp8_fp8(arK[kk][mt], zi_[nt], acci[mt][nt], 0, 0, 0);
                acci[mt][nt] = __builtin_amdgcn_mfma_f32_16x16x32_fp8_fp8(aiK[kk][mt], zr[nt],  acci[mt][nt], 0, 0, 0);
            }
        }
    }
    __syncthreads();
    // ---- epilogue 1: t = z - Az/S, fp8, written IN PLACE over z ----
#pragma unroll
    for (int mt = 0; mt < 2; mt++)
#pragma unroll
        for (int nt = 0; nt < 2; nt++) {
            int c0 = w*32 + mt*16 + hi*4;
            int b  = nt*16 + lo;
            int duc = b*32 + ((c0 >> 3) ^ (b & 7));
            int sel = (c0 >> 2) & 1;
            uint2 q0 = lz8[0][duc], q1 = lz8[1][duc];
            unsigned qr = sel ? q0.y : q0.x;
            unsigned qi = sel ? q1.y : q1.x;
            float zfr[4] = { e4m3f(qr & 0xffu), e4m3f((qr>>8)&0xffu),
                             e4m3f((qr>>16)&0xffu), e4m3f(qr>>24) };
            float zfi[4] = { e4m3f(qi & 0xffu), e4m3f((qi>>8)&0xffu),
                             e4m3f((qi>>16)&0xffu), e4m3f(qi>>24) };
            float vr[4], vi[4];
#pragma unroll
            for (int jj = 0; jj < 4; jj++) {
                vr[jj] = zfr[jj] - accr[mt][nt][jj] * INV_ASCALE;
                vi[jj] = zfi[jj] - acci[mt][nt][jj] * INV_ASCALE;
            }
            ((unsigned int*)&lz8[0][duc])[sel] = pk4_e4m3(vr);
            ((unsigned int*)&lz8[1][duc])[sel] = pk4_e4m3(vi);
        }
    __syncthreads();
    // ---- matmul 2: acc = A * t (A from registers) ----
#pragma unroll
    for (int mt = 0; mt < 2; mt++)
#pragma unroll
        for (int nt = 0; nt < 2; nt++) { accr[mt][nt] = zz; acci[mt][nt] = zz; }
#pragma unroll
    for (int kk = 0; kk < 8; kk++) {
        long zr[2], zi_[2];
#pragma unroll
        for (int nt = 0; nt < 2; nt++) {
            int b = nt*16 + lo;
            int du = b*32 + ((kk*4 + hi) ^ (b & 7));
            zr[nt]  = __builtin_bit_cast(long, lz8[0][du]);
            zi_[nt] = __builtin_bit_cast(long, lz8[1][du]);
        }
#pragma unroll
        for (int mt = 0; mt < 2; mt++) {
            uint2 vb = __builtin_bit_cast(uint2, aiK[kk][mt]);
            long ain = __builtin_bit_cast(long, make_uint2(vb.x ^ 0x80808080u, vb.y ^ 0x80808080u));
#pragma unroll
            for (int nt = 0; nt < 2; nt++) {
                accr[mt][nt] = __builtin_amdgcn_mfma_f32_16x16x32_fp8_fp8(arK[kk][mt], zr[nt],  accr[mt][nt], 0, 0, 0);
                accr[mt][nt] = __builtin_amdgcn_mfma_f32_16x16x32_fp8_fp8(ain,        zi_[nt], accr[mt][nt], 0, 0, 0);
                acci[mt][nt] = __builtin_amdgcn_mfma_f32_16x16x32_fp8_fp8(arK[kk][mt], zi_[nt], acci[mt][nt], 0, 0, 0);
                acci[mt][nt] = __builtin_amdgcn_mfma_f32_16x16x32_fp8_fp8(aiK[kk][mt], zr[nt],  acci[mt][nt], 0, 0, 0);
            }
        }
    }
    __syncthreads();
    // ---- epilogue 2: wx = z32 - 2 acc/S; write bf16 wx into LDS ----
#pragma unroll
    for (int mt = 0; mt < 2; mt++)
#pragma unroll
        for (int nt = 0; nt < 2; nt++) {
            int c0 = w*32 + mt*16 + hi*4;
            int b  = nt*16 + lo;
            size_t zb = ((size_t)f*NB + b)*NCH + c0;
            float4 z4r = *(const float4*)(z32r + zb);
            float4 z4i = *(const float4*)(z32i + zb);
            const float k2 = 2.f * INV_ASCALE;
            float vr[4] = { z4r.x - k2*accr[mt][nt][0], z4r.y - k2*accr[mt][nt][1],
                            z4r.z - k2*accr[mt][nt][2], z4r.w - k2*accr[mt][nt][3] };
            float vi[4] = { z4i.x - k2*acci[mt][nt][0], z4i.y - k2*acci[mt][nt][1],
                            z4i.z - k2*acci[mt][nt][2], z4i.w - k2*acci[mt][nt][3] };
            int o16c = c0 >> 3;
            int duc = b*32 + (o16c ^ (b & 7));
            int sel = (c0 >> 2) & 1;
            ((uint2*)&lw[0][duc])[sel] = make_uint2(pack2(vr[0], vr[1]), pack2(vr[2], vr[3]));
            ((uint2*)&lw[1][duc])[sel] = make_uint2(pack2(vi[0], vi[1]), pack2(vi[2], vi[3]));
        }
    __syncthreads();
    // ---- matmul 3: wxh = H * wx (bf16) ----
#pragma unroll
    for (int mt = 0; mt < 2; mt++)
#pragma unroll
        for (int nt = 0; nt < 2; nt++) { accr[mt][nt] = zz; acci[mt][nt] = zz; }
#pragma unroll
    for (int kk = 0; kk < 8; kk++) {
        bf16x8 hm[2];
#pragma unroll
        for (int mt = 0; mt < 2; mt++) {
            int mtg = w*2 + mt;
            hm[mt] = __builtin_bit_cast(bf16x8, H4[((size_t)kk*16 + mtg)*64 + lane]);
        }
        bf16x8 zr[2], zi_[2];
#pragma unroll
        for (int nt = 0; nt < 2; nt++) {
            int b = nt*16 + lo;
            int du = b*32 + ((kk*4 + hi) ^ (b & 7));
            zr[nt]  = __builtin_bit_cast(bf16x8, lw[0][du]);
            zi_[nt] = __builtin_bit_cast(bf16x8, lw[1][du]);
        }
#pragma unroll
        for (int mt = 0; mt < 2; mt++)
#pragma unroll
            for (int nt = 0; nt < 2; nt++) {
                accr[mt][nt] = __builtin_amdgcn_mfma_f32_16x16x32_bf16(hm[mt], zr[nt],  accr[mt][nt], 0, 0, 0);
                acci[mt][nt] = __builtin_amdgcn_mfma_f32_16x16x32_bf16(hm[mt], zi_[nt], acci[mt][nt], 0, 0, 0);
            }
    }
    // ---- epilogue 3: wxh bf16 planes, [f][b][o] layout ----
#pragma unroll
    for (int mt = 0; mt < 2; mt++)
#pragma unroll
        for (int nt = 0; nt < 2; nt++) {
            int o0 = w*32 + mt*16 + hi*4;
            int b  = nt*16 + lo;
            size_t zb = ((size_t)f*NB + b)*NCH + o0;
            *(uint2*)(wxhR + zb) = make_uint2(pack2(accr[mt][nt][0], accr[mt][nt][1]),
                                              pack2(accr[mt][nt][2], accr[mt][nt][3]));
            *(uint2*)(wxhI + zb) = make_uint2(pack2(acci[mt][nt][0], acci[mt][nt][1]),
                                              pack2(acci[mt][nt][2], acci[mt][nt][3]));
        }
}

// ---------------- fused inverse 2D FFT + bias: wxh -> out[b][o][r][s] ----------------
// Register-disciplined redo of R14: grid 1024, one (r,obl) per thread, NO pass
// loop; i-symmetry folds twiddles to erc/ers[16]. Live set ~ y[32]+32+misc < 110.
__global__ __launch_bounds__(256) void ifft2d(const unsigned short* __restrict__ YR,
                                              const unsigned short* __restrict__ YI,
                                              const float* __restrict__ bias,
                                              float* __restrict__ out)
{
    __shared__ unsigned int Yp[NF * 8];    // 17,408 B, packed (Yr | Yi<<16)
    __shared__ float wcS[32], wsS[32];
    int t = threadIdx.x;
    int ob0 = blockIdx.x * 8;
    if (t < 32) { wcS[t] = COS32[t]; wsS[t] = SIN32[t]; }
#pragma unroll
    for (int it = 0; it < 3; it++) {
        int f = it*256 + t;
        if (f < NF) {
            uint4 vr = *(const uint4*)(YR + (size_t)f*8192 + ob0);
            uint4 vi = *(const uint4*)(YI + (size_t)f*8192 + ob0);
            unsigned int* dst = &Yp[f*8];
            dst[0] = (vr.x & 0xffffu) | (vi.x << 16);
            dst[1] = (vr.x >> 16)     | (vi.x & 0xffff0000u);
            dst[2] = (vr.y & 0xffffu) | (vi.y << 16);
            dst[3] = (vr.y >> 16)     | (vi.y & 0xffff0000u);
            dst[4] = (vr.z & 0xffffu) | (vi.z << 16);
            dst[5] = (vr.z >> 16)     | (vi.z & 0xffff0000u);
            dst[6] = (vr.w & 0xffffu) | (vi.w << 16);
            dst[7] = (vr.w >> 16)     | (vi.w & 0xffff0000u);
        }
    }
    __syncthreads();
    int r = t & 31, obl = t >> 5;
    float sr = (r & 1) ? -1.f : 1.f;       // (-1)^r for i-fold
    float erc[16], ers[16];                // e^{+2pi i (i*r)/32}, i<16
#pragma unroll
    for (int i = 0; i < 16; i++) {
        int m = (i * r) & 31;
        erc[i] = wcS[m]; ers[i] = wsS[m];
    }
    float y[32];
#pragma unroll
    for (int s = 0; s < 32; s++) y[s] = 0.f;
#pragma unroll
    for (int j = 0; j < 17; j++) {
        float Gr = 0.f, Gi = 0.f;
#pragma unroll
        for (int i = 0; i < 16; i++) {
            unsigned p1 = Yp[(i*17 + j)*8 + obl];          // broadcast reads
            unsigned p2 = Yp[((i+16)*17 + j)*8 + obl];
            float Yx = bf2f(p1 & 0xffffu) + sr * bf2f(p2 & 0xffffu);
            float Yy = bf2f(p1 >> 16)     + sr * bf2f(p2 >> 16);
            Gr += Yx*erc[i] - Yy*ers[i];
            Gi += Yx*ers[i] + Yy*erc[i];
        }
        if (j == 0) {
#pragma unroll
            for (int s = 0; s < 32; s++) y[s] += Gr;
        } else if (j == 16) {
#pragma unroll
            for (int s = 0; s < 32; s++) y[s] += (s & 1) ? -Gr : Gr;
        } else {
#pragma unroll
            for (int s = 0; s < 32; s++) {
                int m = (j * s) & 31;                      // compile-time constant
                y[s] += 2.f * (Gr * COS32[m] - Gi * SIN32[m]);
            }
        }
    }
    int ob = ob0 + obl;
    int b = ob >> 8, o = ob & 255;
    float bv = bias[o];
    float* op = out + ((size_t)(b * NCH + o) * 32 + r) * 32;
#pragma unroll
    for (int s = 0; s < 32; s++) op[s] = y[s] * (1.f/1024.f) + bv;
}

extern "C" void kernel_launch(void* const* d_in, const int* in_sizes, int n_in,
                              void* d_out, int out_size, void* d_ws, size_t ws_size,
                              hipStream_t stream) {
    (void)in_sizes; (void)n_in; (void)out_size;
    if (ws_size < WS_NEED) return;

    const float* x     = (const float*)d_in[0];
    const float* w     = (const float*)d_in[1];
    const float* alpha = (const float*)d_in[2];
    const float* H     = (const float*)d_in[3];
    const float* bias  = (const float*)d_in[4];
    float* out = (float*)d_out;

    char* ws = (char*)d_ws;
    unsigned char* Afrag = (unsigned char*)(ws + OFF_AFRAG);
    float2* tmp = (float2*)(ws + OFF_AFRAG);   // dead before a_build writes Afrag
    unsigned char* z8r  = (unsigned char*)(ws + OFF_Z8R);
    unsigned char* z8i  = (unsigned char*)(ws + OFF_Z8I);
    float* z32r = (float*)(ws + OFF_Z32R);
    float* z32i = (float*)(ws + OFF_Z32I);
    unsigned short* wxhR = (unsigned short*)(ws + OFF_WXHR);
    unsigned short* wxhI = (unsigned short*)(ws + OFF_WXHI);
    unsigned short* Hfrag = (unsigned short*)(ws + OFF_HFRAG);
    float* red = (float*)(ws + OFF_RED);
    float* sig = red + 256;

    norm_part<<<256, 256, 0, stream>>>(w, red);
    norm_final<<<1, 256, 0, stream>>>(red, alpha, sig);
    hfrag_build<<<dim3(8, 16), 64, 0, stream>>>(H, Hfrag);

    rfft2_reg<<<1024, 256, 0, stream>>>(x, tmp);
    transpose_z<<<dim3(8, 17, 32), 256, 0, stream>>>(tmp, z32r, z32i, z8r, z8i);

    a_build_direct<<<dim3(16, 8, 17), 256, 0, stream>>>(w, sig, (unsigned int*)Afrag);
    neum_fused<<<NF, 512, 0, stream>>>(Afrag, Hfrag, z8r, z8i, z32r, z32i, wxhR, wxhI);

    ifft2d<<<1024, 256, 0, stream>>>(wxhR, wxhI, bias, out);
}

// Round 17
// 171.924 us; speedup vs baseline: 1.1962x; 1.1962x over previous
//
#include <hip/hip_runtime.h>
#include <hip/hip_fp8.h>
#include <cstddef>

#define PI_F 3.14159265358979323846f

#define NCH 256   // C
#define NB  32    // B
#define NF  544   // n*(n/2+1),  f = i*17 + j

#define ASCALE     65536.0f
#define INV_ASCALE (1.0f/65536.0f)

typedef short  bf16x8 __attribute__((ext_vector_type(8)));
typedef float  f32x4  __attribute__((ext_vector_type(4)));

// ---- workspace layout (bytes), single-chunk, fp8 A ----
#define SZ_AFRAG ((size_t)NF*8*16*1024)         // 71,303,168 (fp8 fragments; tmp & G alias)
#define SZ_P8    ((size_t)NF*NB*NCH)            // 4,456,448  (fp8 plane)
#define SZ_PB    ((size_t)NF*NB*NCH*2)          // 8,912,896  (bf16 plane)
#define SZ_P32   ((size_t)NF*NB*NCH*4)          // 17,825,792 (fp32 plane)
#define OFF_AFRAG ((size_t)0)
#define OFF_Z8R  (OFF_AFRAG + SZ_AFRAG)
#define OFF_Z8I  (OFF_Z8R + SZ_P8)
#define OFF_Z32R (OFF_Z8I + SZ_P8)
#define OFF_Z32I (OFF_Z32R + SZ_P32)
#define OFF_WXHR (OFF_Z32I + SZ_P32)
#define OFF_WXHI (OFF_WXHR + SZ_PB)
#define OFF_HFRAG (OFF_WXHI + SZ_PB)
#define SZ_HFRAG ((size_t)8*16*1024)            // 131,072
#define OFF_RED  (OFF_HFRAG + SZ_HFRAG)
#define WS_NEED  (OFF_RED + (size_t)4096)       // ~134 MB

// 32-point twiddle tables: COS32[k]=cos(2pi k/32), SIN32[k]=sin(2pi k/32)
__device__ constexpr float COS32[32] = {
     1.0000000000f,  0.9807852804f,  0.9238795325f,  0.8314696123f,
     0.7071067812f,  0.5555702330f,  0.3826834324f,  0.1950903220f,
     0.0000000000f, -0.1950903220f, -0.3826834324f, -0.5555702330f,
    -0.7071067812f, -0.8314696123f, -0.9238795325f, -0.9807852804f,
    -1.0000000000f, -0.9807852804f, -0.9238795325f, -0.8314696123f,
    -0.7071067812f, -0.5555702330f, -0.3826834324f, -0.1950903220f,
    -0.0000000000f,  0.1950903220f,  0.3826834324f,  0.5555702330f,
     0.7071067812f,  0.8314696123f,  0.9238795325f,  0.9807852804f };
__device__ constexpr float SIN32[32] = {
     0.0000000000f,  0.1950903220f,  0.3826834324f,  0.5555702330f,
     0.7071067812f,  0.8314696123f,  0.9238795325f,  0.9807852804f,
     1.0000000000f,  0.9807852804f,  0.9238795325f,  0.8314696123f,
     0.7071067812f,  0.5555702330f,  0.3826834324f,  0.1950903220f,
     0.0000000000f, -0.1950903220f, -0.3826834324f, -0.5555702330f,
    -0.7071067812f, -0.8314696123f, -0.9238795325f, -0.9807852804f,
    -1.0000000000f, -0.9807852804f, -0.9238795325f, -0.8314696123f,
    -0.7071067812f, -0.5555702330f, -0.3826834324f, -0.1950903220f };

__device__ __forceinline__ unsigned short f2bf(float x) {
    unsigned int u = __float_as_uint(x);
    u += 0x7FFFu + ((u >> 16) & 1u);            // RNE
    return (unsigned short)(u >> 16);
}
__device__ __forceinline__ float bf2f(unsigned int h) {
    return __uint_as_float(h << 16);
}
__device__ __forceinline__ unsigned int pack2(float a, float b) {
    return (unsigned int)f2bf(a) | ((unsigned int)f2bf(b) << 16);
}
__device__ __forceinline__ unsigned char f2e4m3(float x) {
    __hip_fp8_e4m3 h(x);
    return (unsigned char)h.__x;
}
__device__ __forceinline__ float e4m3f(unsigned int b) {
    __hip_fp8_e4m3 h; h.__x = (__hip_fp8_storage_t)b;
    return (float)h;
}
__device__ __forceinline__ unsigned int pk4_e4m3(const float* v) {
    return (unsigned)f2e4m3(v[0]) | ((unsigned)f2e4m3(v[1]) << 8) |
           ((unsigned)f2e4m3(v[2]) << 16) | ((unsigned)f2e4m3(v[3]) << 24);
}

// ---------------- norm of wfft (closed form via Parseval) ----------------
__global__ void norm_part(const float* __restrict__ w, float* __restrict__ red) {
    int idx = blockIdx.x * 256 + threadIdx.x;
    const float* wp = w + (size_t)idx * 9;
    float s2 = 0.f, aa = 0.f, bb = 0.f;
#pragma unroll
    for (int u = 0; u < 3; u++) {
        float w0 = wp[u*3+0], w1 = wp[u*3+1], w2 = wp[u*3+2];
        s2 += w0*w0 + w1*w1 + w2*w2;
        float au = w0 + w1 + w2, bu = w0 - w1 + w2;
        aa += au*au; bb += bu*bu;
    }
    float p = 512.f*s2 + 16.f*(aa + bb);
    __shared__ float sm[256];
    sm[threadIdx.x] = p; __syncthreads();
    for (int s = 128; s > 0; s >>= 1) {
        if (threadIdx.x < s) sm[threadIdx.x] += sm[threadIdx.x + s];
        __syncthreads();
    }
    if (threadIdx.x == 0) red[blockIdx.x] = sm[0];
}

__global__ void norm_final(const float* __restrict__ red, const float* __restrict__ alpha,
                           float* __restrict__ sig) {
    __shared__ float sm[256];
    sm[threadIdx.x] = red[threadIdx.x]; __syncthreads();
    for (int s = 128; s > 0; s >>= 1) {
        if (threadIdx.x < s) sm[threadIdx.x] += sm[threadIdx.x + s];
        __syncthreads();
    }
    if (threadIdx.x == 0) sig[0] = alpha[0] / sqrtf(sm[0]);
}

// ---------------- H fragments (A-operand: m=o, k=c), bf16 ----------------
__global__ void hfrag_build(const float* __restrict__ H, unsigned short* __restrict__ Hfrag) {
    int kk = blockIdx.x, mt = blockIdx.y, lane = threadIdx.x;   // 64 threads
    int o = mt*16 + (lane & 15), c0 = kk*32 + (lane >> 4)*8;
    const float* hp = H + (size_t)o*NCH + c0;
    uint4 u;
    u.x = pack2(hp[0], hp[1]); u.y = pack2(hp[2], hp[3]);
    u.z = pack2(hp[4], hp[5]); u.w = pack2(hp[6], hp[7]);
    ((uint4*)Hfrag)[((size_t)kk*16 + mt)*64 + lane] = u;
}

// ---------------- rfft2: register-resident DFT, 8 tiles per 256-thread block ----------------
__global__ __launch_bounds__(256) void rfft2_reg(const float* __restrict__ x,
                                                 float2* __restrict__ tmp)
{
    __shared__ float2 T[8][544];       // [half][r*17+j], ~35 KB
    __shared__ float2 Z[8][544];       // output staging, ~35 KB
    __shared__ float wc[32], wsn[32];
    int t = threadIdx.x;
    int half = t >> 5, lane = t & 31;
    int cb = blockIdx.x * 8 + half;    // tile index in tmp order: cb = c*32 + b
    int c = cb >> 5, b = cb & 31;
    if (t < 32) { wc[t] = COS32[t]; wsn[t] = SIN32[t]; }
    float xr[32];
    const float* xp = x + ((size_t)(b * NCH + c)) * 1024 + lane * 32;
#pragma unroll
    for (int q = 0; q < 8; q++) {
        float4 v = *(const float4*)(xp + q*4);
        xr[q*4+0] = v.x; xr[q*4+1] = v.y; xr[q*4+2] = v.z; xr[q*4+3] = v.w;
    }
    float x0v = xr[0], x16v = xr[16];
    float es[15], os[15];
#pragma unroll
    for (int s = 1; s <= 15; s++) { es[s-1] = xr[s] + xr[32-s]; os[s-1] = xr[s] - xr[32-s]; }
#pragma unroll
    for (int j = 0; j < 17; j++) {
        float ax = x0v + ((j & 1) ? -x16v : x16v);
        float ay = 0.f;
#pragma unroll
        for (int s = 1; s <= 15; s++) {
            int m = (j * s) & 31;
            ax += es[s-1] * COS32[m];
            ay -= os[s-1] * SIN32[m];
        }
        T[half][lane*17 + j] = make_float2(ax, ay);
    }
    __syncthreads();
    float wr_[16], wi_[16];
#pragma unroll
    for (int r = 0; r < 16; r++) {
        int m = (lane * r) & 31;
        wr_[r] = wc[m]; wi_[r] = wsn[m];
    }
    float sgn = (lane & 1) ? -1.f : 1.f;    // (-1)^i
#pragma unroll
    for (int j = 0; j < 17; j++) {
        float ax = 0.f, ay = 0.f;
#pragma unroll
        for (int r = 0; r < 16; r++) {
            float2 t1 = T[half][r*17 + j];
            float2 t2 = T[half][(r+16)*17 + j];
            float ex = fmaf(sgn, t2.x, t1.x);
            float ey = fmaf(sgn, t2.y, t1.y);
            ax += ex * wr_[r] + ey * wi_[r];
            ay += ey * wr_[r] - ex * wi_[r];
        }
        Z[half][lane*17 + j] = make_float2(ax, ay);
    }
    __syncthreads();
    float2* outp = tmp + (size_t)blockIdx.x * 8 * 544;
    const float2* zf = (const float2*)Z;
#pragma unroll
    for (int u = 0; u < 17; u++)
        outp[u*256 + t] = zf[u*256 + t];
}

// ---------------- transpose tmp[cb][f] -> fp32 planes + fp8 planes [f][b][c] ----------------
__global__ __launch_bounds__(256) void transpose_z(const float2* __restrict__ tmp,
        float* __restrict__ z32r, float* __restrict__ z32i,
        unsigned char* __restrict__ z8r, unsigned char* __restrict__ z8i)
{
    __shared__ float2 tile[32][33];
    int ct = blockIdx.x, ft = blockIdx.y, b = blockIdx.z;
    int t = threadIdx.x;
#pragma unroll
    for (int it = 0; it < 4; it++) {
        int idx = t + it*256; int cl = idx >> 5, fl = idx & 31;
        tile[cl][fl] = tmp[((size_t)((ct*32 + cl)*32 + b))*544 + ft*32 + fl];
    }
    __syncthreads();
#pragma unroll
    for (int it = 0; it < 4; it++) {
        int idx = t + it*256; int fl = idx >> 5, cl = idx & 31;
        float2 v = tile[cl][fl];
        size_t zi_ = ((size_t)(ft*32 + fl)*NB + b)*NCH + ct*32 + cl;
        z32r[zi_] = v.x; z32i[zi_] = v.y;
        z8r[zi_] = f2e4m3(v.x); z8i[zi_] = f2e4m3(v.y);
    }
}

// ---------------- A-build, factorized + direct fragment writes ----------------
__global__ __launch_bounds__(256) void a_build_direct(const float* __restrict__ w,
        const float* __restrict__ sig, unsigned int* __restrict__ Afrag)
{
    int mt = blockIdx.x, kk = blockIdx.y, j = blockIdx.z;   // 16, 8, 17
    int t = threadIdx.x;
    int wv = t & 127;
    int c   = mt*16 + ((wv >> 1) & 15);
    int cp0 = kk*32 + (wv >> 5)*8 + (wv & 1)*4;
    bool isReal = (t < 128);
    float sS = sig[0] * ASCALE;
    float sgnS = isReal ? sS : -sS;
    f32x4 P1, P2, P3, P4, P5;
#pragma unroll
    for (int e = 0; e < 4; e++) {
        int cp = cp0 + e;
        const float* p1 = w + ((size_t)c*NCH + cp)*9;
        const float* p2 = w + ((size_t)cp*NCH + c)*9;
        float u_[9];
#pragma unroll
        for (int q = 0; q < 9; q++)
            u_[q] = isReal ? (p1[q] - p2[q]) : (p1[q] + p2[q]);
        if (isReal) {
            P1[e] = sgnS * u_[4];
            P2[e] = sgnS * (u_[3] + u_[5]);
            P3[e] = sgnS * (u_[1] + u_[7]);
            P4[e] = sgnS * (u_[0] + u_[2] + u_[6] + u_[8]);
            P5[e] = sgnS * ((u_[6] - u_[8]) - (u_[0] - u_[2]));
        } else {
            P1[e] = sgnS * (u_[3] - u_[5]);
            P2[e] = sgnS * ((u_[0] - u_[2]) + (u_[6] - u_[8]));
            P3[e] = sgnS * (u_[1] - u_[7]);
            P4[e] = sgnS * ((u_[0] + u_[2]) - (u_[6] + u_[8]));
            P5[e] = 0.f;
        }
    }
    float cps = COS32[j], sns = SIN32[j];
    f32x4 Aj, Bj, Cj;
    if (isReal) { Aj = P1 + cps*P2; Bj = P3 + cps*P4; Cj = sns*P5; }
    else        { Aj = sns*P1;      Bj = sns*P2;      Cj = P3 + cps*P4; }
    unsigned int* out = Afrag + ((size_t)j*128 + kk*16 + mt)*256 + t;
#pragma unroll
    for (int i = 0; i < 32; i++) {
        f32x4 v = Aj + COS32[i]*Bj + SIN32[i]*Cj;   // compile-time twiddles
        *out = (unsigned)f2e4m3(v[0]) | ((unsigned)f2e4m3(v[1]) << 8)
             | ((unsigned)f2e4m3(v[2]) << 16) | ((unsigned)f2e4m3(v[3]) << 24);
        out += (size_t)17*32768;   // fl = i*17 + j
    }
}

// ---------------- neum_fused: t = z - A z ; wx = z32 - 2 A t ; wxh = H wx ----------------
// A fragments loaded ONCE into registers and reused for both matmuls.
__global__ __launch_bounds__(512) void neum_fused(
    const unsigned char* __restrict__ Afrag,
    const unsigned short* __restrict__ Hfrag,
    const unsigned char* __restrict__ z8r, const unsigned char* __restrict__ z8i,
    const float* __restrict__ z32r, const float* __restrict__ z32i,
    unsigned short* __restrict__ wxhR, unsigned short* __restrict__ wxhI)
{
    __shared__ uint2 lz8[2][1024];   // 16 KB: fp8 z, then fp8 t (in-place)
    __shared__ uint4 lw[2][1024];    // 32 KB: bf16 wx
    int fl = blockIdx.x;
    int f = fl;
    int t = threadIdx.x;
    const uint2* s0 = (const uint2*)(z8r + (size_t)f*8192);
    const uint2* s1 = (const uint2*)(z8i + (size_t)f*8192);
    for (int u = t; u < 2048; u += 512) {
        int p = u >> 10, idx = u & 1023;
        int b = idx >> 5, o16 = idx & 31;
        lz8[p][b*32 + (o16 ^ (b & 7))] = (p ? s1 : s0)[idx];
    }
    int w = t >> 6, lane = t & 63, lo = lane & 15, hi = lane >> 4;
    const uint2* A8 = (const uint2*)Afrag;
    const uint4* H4 = (const uint4*)Hfrag;
    long arK[8][2], aiK[8][2];
#pragma unroll
    for (int kk = 0; kk < 8; kk++) {
#pragma unroll
        for (int mt = 0; mt < 2; mt++) {
            int mtg = w*2 + mt;
            size_t idx = (((size_t)fl*8 + kk)*16 + mtg)*128 + lane;
            arK[kk][mt] = __builtin_bit_cast(long, A8[idx]);
            aiK[kk][mt] = __builtin_bit_cast(long, A8[idx + 64]);
        }
    }
    __syncthreads();
    f32x4 accr[2][2], acci[2][2];
    f32x4 zz = {0.f, 0.f, 0.f, 0.f};
#pragma unroll
    for (int mt = 0; mt < 2; mt++)
#pragma unroll
        for (int nt = 0; nt < 2; nt++) { accr[mt][nt] = zz; acci[mt][nt] = zz; }
    // ---- matmul 1: acc = A * z (fp8) ----
#pragma unroll
    for (int kk = 0; kk < 8; kk++) {
        long zr[2], zi_[2];
#pragma unroll
        for (int nt = 0; nt < 2; nt++) {
            int b = nt*16 + lo;
            int du = b*32 + ((kk*4 + hi) ^ (b & 7));
            zr[nt]  = __builtin_bit_cast(long, lz8[0][du]);
            zi_[nt] = __builtin_bit_cast(long, lz8[1][du]);
        }
#pragma unroll
        for (int mt = 0; mt < 2; mt++) {
            uint2 vb = __builtin_bit_cast(uint2, aiK[kk][mt]);
            long ain = __builtin_bit_cast(long, make_uint2(vb.x ^ 0x80808080u, vb.y ^ 0x80808080u));
#pragma unroll
            for (int nt = 0; nt < 2; nt++) {
                accr[mt][nt] = __builtin_amdgcn_mfma_f32_16x16x32_fp8_fp8(arK[kk][mt], zr[nt],  accr[mt][nt], 0, 0, 0);
                accr[mt][nt] = __builtin_amdgcn_mfma_f32_16x16x32_fp8_fp8(ain,        zi_[nt], accr[mt][nt], 0, 0, 0);
                acci[mt][nt] = __builtin_amdgcn_mfma_f32_16x16x32_fp8_fp8(arK[kk][mt], zi_[nt], acci[mt][nt], 0, 0, 0);
                acci[mt][nt] = __builtin_amdgcn_mfma_f32_16x16x32_fp8_fp8(aiK[kk][mt], zr[nt],  acci[mt][nt], 0, 0, 0);
            }
        }
    }
    __syncthreads();
    // ---- epilogue 1: t = z - Az/S, fp8, written IN PLACE over z ----
#pragma unroll
    for (int mt = 0; mt < 2; mt++)
#pragma unroll
        for (int nt = 0; nt < 2; nt++) {
            int c0 = w*32 + mt*16 + hi*4;
            int b  = nt*16 + lo;
            int duc = b*32 + ((c0 >> 3) ^ (b & 7));
            int sel = (c0 >> 2) & 1;
            uint2 q0 = lz8[0][duc], q1 = lz8[1][duc];
            unsigned qr = sel ? q0.y : q0.x;
            unsigned qi = sel ? q1.y : q1.x;
            float zfr[4] = { e4m3f(qr & 0xffu), e4m3f((qr>>8)&0xffu),
                             e4m3f((qr>>16)&0xffu), e4m3f(qr>>24) };
            float zfi[4] = { e4m3f(qi & 0xffu), e4m3f((qi>>8)&0xffu),
                             e4m3f((qi>>16)&0xffu), e4m3f(qi>>24) };
            float vr[4], vi[4];
#pragma unroll
            for (int jj = 0; jj < 4; jj++) {
                vr[jj] = zfr[jj] - accr[mt][nt][jj] * INV_ASCALE;
                vi[jj] = zfi[jj] - acci[mt][nt][jj] * INV_ASCALE;
            }
            ((unsigned int*)&lz8[0][duc])[sel] = pk4_e4m3(vr);
            ((unsigned int*)&lz8[1][duc])[sel] = pk4_e4m3(vi);
        }
    __syncthreads();
    // ---- matmul 2: acc = A * t (A from registers) ----
#pragma unroll
    for (int mt = 0; mt < 2; mt++)
#pragma unroll
        for (int nt = 0; nt < 2; nt++) { accr[mt][nt] = zz; acci[mt][nt] = zz; }
#pragma unroll
    for (int kk = 0; kk < 8; kk++) {
        long zr[2], zi_[2];
#pragma unroll
        for (int nt = 0; nt < 2; nt++) {
            int b = nt*16 + lo;
            int du = b*32 + ((kk*4 + hi) ^ (b & 7));
            zr[nt]  = __builtin_bit_cast(long, lz8[0][du]);
            zi_[nt] = __builtin_bit_cast(long, lz8[1][du]);
        }
#pragma unroll
        for (int mt = 0; mt < 2; mt++) {
            uint2 vb = __builtin_bit_cast(uint2, aiK[kk][mt]);
            long ain = __builtin_bit_cast(long, make_uint2(vb.x ^ 0x80808080u, vb.y ^ 0x80808080u));
#pragma unroll
            for (int nt = 0; nt < 2; nt++) {
                accr[mt][nt] = __builtin_amdgcn_mfma_f32_16x16x32_fp8_fp8(arK[kk][mt], zr[nt],  accr[mt][nt], 0, 0, 0);
                accr[mt][nt] = __builtin_amdgcn_mfma_f32_16x16x32_fp8_fp8(ain,        zi_[nt], accr[mt][nt], 0, 0, 0);
                acci[mt][nt] = __builtin_amdgcn_mfma_f32_16x16x32_fp8_fp8(arK[kk][mt], zi_[nt], acci[mt][nt], 0, 0, 0);
                acci[mt][nt] = __builtin_amdgcn_mfma_f32_16x16x32_fp8_fp8(aiK[kk][mt], zr[nt],  acci[mt][nt], 0, 0, 0);
            }
        }
    }
    __syncthreads();
    // ---- epilogue 2: wx = z32 - 2 acc/S; write bf16 wx into LDS ----
#pragma unroll
    for (int mt = 0; mt < 2; mt++)
#pragma unroll
        for (int nt = 0; nt < 2; nt++) {
            int c0 = w*32 + mt*16 + hi*4;
            int b  = nt*16 + lo;
            size_t zb = ((size_t)f*NB + b)*NCH + c0;
            float4 z4r = *(const float4*)(z32r + zb);
            float4 z4i = *(const float4*)(z32i + zb);
            const float k2 = 2.f * INV_ASCALE;
            float vr[4] = { z4r.x - k2*accr[mt][nt][0], z4r.y - k2*accr[mt][nt][1],
                            z4r.z - k2*accr[mt][nt][2], z4r.w - k2*accr[mt][nt][3] };
            float vi[4] = { z4i.x - k2*acci[mt][nt][0], z4i.y - k2*acci[mt][nt][1],
                            z4i.z - k2*acci[mt][nt][2], z4i.w - k2*acci[mt][nt][3] };
            int o16c = c0 >> 3;
            int duc = b*32 + (o16c ^ (b & 7));
            int sel = (c0 >> 2) & 1;
            ((uint2*)&lw[0][duc])[sel] = make_uint2(pack2(vr[0], vr[1]), pack2(vr[2], vr[3]));
            ((uint2*)&lw[1][duc])[sel] = make_uint2(pack2(vi[0], vi[1]), pack2(vi[2], vi[3]));
        }
    __syncthreads();
    // ---- matmul 3: wxh = H * wx (bf16) ----
#pragma unroll
    for (int mt = 0; mt < 2; mt++)
#pragma unroll
        for (int nt = 0; nt < 2; nt++) { accr[mt][nt] = zz; acci[mt][nt] = zz; }
#pragma unroll
    for (int kk = 0; kk < 8; kk++) {
        bf16x8 hm[2];
#pragma unroll
        for (int mt = 0; mt < 2; mt++) {
            int mtg = w*2 + mt;
            hm[mt] = __builtin_bit_cast(bf16x8, H4[((size_t)kk*16 + mtg)*64 + lane]);
        }
        bf16x8 zr[2], zi_[2];
#pragma unroll
        for (int nt = 0; nt < 2; nt++) {
            int b = nt*16 + lo;
            int du = b*32 + ((kk*4 + hi) ^ (b & 7));
            zr[nt]  = __builtin_bit_cast(bf16x8, lw[0][du]);
            zi_[nt] = __builtin_bit_cast(bf16x8, lw[1][du]);
        }
#pragma unroll
        for (int mt = 0; mt < 2; mt++)
#pragma unroll
            for (int nt = 0; nt < 2; nt++) {
                accr[mt][nt] = __builtin_amdgcn_mfma_f32_16x16x32_bf16(hm[mt], zr[nt],  accr[mt][nt], 0, 0, 0);
                acci[mt][nt] = __builtin_amdgcn_mfma_f32_16x16x32_bf16(hm[mt], zi_[nt], acci[mt][nt], 0, 0, 0);
            }
    }
    // ---- epilogue 3: wxh bf16 planes, [f][b][o] layout ----
#pragma unroll
    for (int mt = 0; mt < 2; mt++)
#pragma unroll
        for (int nt = 0; nt < 2; nt++) {
            int o0 = w*32 + mt*16 + hi*4;
            int b  = nt*16 + lo;
            size_t zb = ((size_t)f*NB + b)*NCH + o0;
            *(uint2*)(wxhR + zb) = make_uint2(pack2(accr[mt][nt][0], accr[mt][nt][1]),
                                              pack2(accr[mt][nt][2], accr[mt][nt][3]));
            *(uint2*)(wxhI + zb) = make_uint2(pack2(acci[mt][nt][0], acci[mt][nt][1]),
                                              pack2(acci[mt][nt][2], acci[mt][nt][3]));
        }
}

// ---------------- pass I: complex ifft along i -> G[j][r][ob] (coalesced stores) ----------------
template<int RH>
__device__ __forceinline__ void ifft_i_body(const unsigned short* __restrict__ YR,
                                            const unsigned short* __restrict__ YI,
                                            float2* __restrict__ G, int j, int ob)
{
    float2 Gacc[16];
#pragma unroll
    for (int rr = 0; rr < 16; rr++) Gacc[rr] = make_float2(0.f, 0.f);
#pragma unroll
    for (int i = 0; i < 32; i++) {
        size_t yi_ = (size_t)(i * 17 + j) * 8192 + ob;
        float Yx = bf2f(YR[yi_]);
        float Yy = bf2f(YI[yi_]);
#pragma unroll
        for (int rr = 0; rr < 16; rr++) {
            int m = (i * (RH * 16 + rr)) & 31;     // compile-time constant
            Gacc[rr].x += Yx*COS32[m] - Yy*SIN32[m];
            Gacc[rr].y += Yx*SIN32[m] + Yy*COS32[m];
        }
    }
#pragma unroll
    for (int rr = 0; rr < 16; rr++) {
        G[((size_t)(j*32 + RH*16 + rr))*8192 + ob] =
            make_float2(Gacc[rr].x * (1.f/32.f), Gacc[rr].y * (1.f/32.f));
    }
}

__global__ __launch_bounds__(256) void ifft_i(const unsigned short* __restrict__ YR,
                                              const unsigned short* __restrict__ YI,
                                              float2* __restrict__ G) {
    int bid = blockIdx.x;
    int j   = bid >> 6;          // 0..16
    int rh  = (bid >> 5) & 1;    // 0..1
    int obc = bid & 31;          // 0..31
    int ob  = obc * 256 + threadIdx.x;
    if (rh == 0) ifft_i_body<0>(YR, YI, G, j, ob);
    else         ifft_i_body<1>(YR, YI, G, j, ob);
}

// ---------------- pass II: irfft along j + bias -> out[b][o][r][s] ----------------
// ob = b*256 + o (plane layout [f][b][o])
__global__ __launch_bounds__(256) void irfft_j(const float2* __restrict__ G,
                                               const float* __restrict__ bias,
                                               float* __restrict__ out) {
    int gid = blockIdx.x * 256 + threadIdx.x;
    int r = gid >> 13, ob = gid & 8191;
    int b = ob >> 8, o = ob & 255;
    float2 Gv[17];
#pragma unroll
    for (int jj = 0; jj < 17; jj++)
        Gv[jj] = G[((size_t)(jj*32 + r))*8192 + ob];
    float y[32];
    float g0 = Gv[0].x, g16 = Gv[16].x;
#pragma unroll
    for (int s = 0; s < 32; s++) y[s] = g0 + ((s & 1) ? -g16 : g16);
#pragma unroll
    for (int jj = 1; jj < 16; jj++) {
#pragma unroll
        for (int s = 0; s < 32; s++) {
            int m = (jj * s) & 31;                 // compile-time constant
            y[s] += 2.f * (Gv[jj].x * COS32[m] - Gv[jj].y * SIN32[m]);
        }
    }
    float bv = bias[o];
    float* op = out + ((size_t)(b * NCH + o) * 32 + r) * 32;
#pragma unroll
    for (int s = 0; s < 32; s++) op[s] = y[s] * (1.f/32.f) + bv;
}

extern "C" void kernel_launch(void* const* d_in, const int* in_sizes, int n_in,
                              void* d_out, int out_size, void* d_ws, size_t ws_size,
                              hipStream_t stream) {
    (void)in_sizes; (void)n_in; (void)out_size;
    if (ws_size < WS_NEED) return;

    const float* x     = (const float*)d_in[0];
    const float* w     = (const float*)d_in[1];
    const float* alpha = (const float*)d_in[2];
    const float* H     = (const float*)d_in[3];
    const float* bias  = (const float*)d_in[4];
    float* out = (float*)d_out;

    char* ws = (char*)d_ws;
    unsigned char* Afrag = (unsigned char*)(ws + OFF_AFRAG);
    float2* tmp = (float2*)(ws + OFF_AFRAG);   // dead before a_build writes Afrag
    float2* G   = (float2*)(ws + OFF_AFRAG);   // live after neum pass (Afrag dead)
    unsigned char* z8r  = (unsigned char*)(ws + OFF_Z8R);
    unsigned char* z8i  = (unsigned char*)(ws + OFF_Z8I);
    float* z32r = (float*)(ws + OFF_Z32R);
    float* z32i = (float*)(ws + OFF_Z32I);
    unsigned short* wxhR = (unsigned short*)(ws + OFF_WXHR);
    unsigned short* wxhI = (unsigned short*)(ws + OFF_WXHI);
    unsigned short* Hfrag = (unsigned short*)(ws + OFF_HFRAG);
    float* red = (float*)(ws + OFF_RED);
    float* sig = red + 256;

    norm_part<<<256, 256, 0, stream>>>(w, red);
    norm_final<<<1, 256, 0, stream>>>(red, alpha, sig);
    hfrag_build<<<dim3(8, 16), 64, 0, stream>>>(H, Hfrag);

    rfft2_reg<<<1024, 256, 0, stream>>>(x, tmp);
    transpose_z<<<dim3(8, 17, 32), 256, 0, stream>>>(tmp, z32r, z32i, z8r, z8i);

    a_build_direct<<<dim3(16, 8, 17), 256, 0, stream>>>(w, sig, (unsigned int*)Afrag);
    neum_fused<<<NF, 512, 0, stream>>>(Afrag, Hfrag, z8r, z8i, z32r, z32i, wxhR, wxhI);

    ifft_i<<<1088, 256, 0, stream>>>(wxhR, wxhI, G);
    irfft_j<<<1024, 256, 0, stream>>>(G, bias, out);
}

// Round 18
// 168.757 us; speedup vs baseline: 1.2186x; 1.0188x over previous
//
#include <hip/hip_runtime.h>
#include <hip/hip_fp8.h>
#include <cstddef>

#define PI_F 3.14159265358979323846f

#define NCH 256   // C
#define NB  32    // B
#define NF  544   // n*(n/2+1),  f = i*17 + j

#define ASCALE     65536.0f
#define INV_ASCALE (1.0f/65536.0f)

typedef short  bf16x8 __attribute__((ext_vector_type(8)));
typedef float  f32x4  __attribute__((ext_vector_type(4)));

// ---- workspace layout (bytes), single-chunk, fp8 A ----
#define SZ_AFRAG ((size_t)NF*8*16*1024)         // 71,303,168 (fp8 fragments; tmp & G alias)
#define SZ_P8    ((size_t)NF*NB*NCH)            // 4,456,448  (fp8 plane)
#define SZ_PB    ((size_t)NF*NB*NCH*2)          // 8,912,896  (bf16 plane)
#define SZ_P32   ((size_t)NF*NB*NCH*4)          // 17,825,792 (fp32 plane)
#define OFF_AFRAG ((size_t)0)
#define OFF_Z8R  (OFF_AFRAG + SZ_AFRAG)
#define OFF_Z8I  (OFF_Z8R + SZ_P8)
#define OFF_Z32R (OFF_Z8I + SZ_P8)
#define OFF_Z32I (OFF_Z32R + SZ_P32)
#define OFF_WXHR (OFF_Z32I + SZ_P32)
#define OFF_WXHI (OFF_WXHR + SZ_PB)
#define OFF_HFRAG (OFF_WXHI + SZ_PB)
#define SZ_HFRAG ((size_t)8*16*1024)            // 131,072
#define OFF_RED  (OFF_HFRAG + SZ_HFRAG)
#define WS_NEED  (OFF_RED + (size_t)4096)       // ~134 MB

// 32-point twiddle tables: COS32[k]=cos(2pi k/32), SIN32[k]=sin(2pi k/32)
__device__ constexpr float COS32[32] = {
     1.0000000000f,  0.9807852804f,  0.9238795325f,  0.8314696123f,
     0.7071067812f,  0.5555702330f,  0.3826834324f,  0.1950903220f,
     0.0000000000f, -0.1950903220f, -0.3826834324f, -0.5555702330f,
    -0.7071067812f, -0.8314696123f, -0.9238795325f, -0.9807852804f,
    -1.0000000000f, -0.9807852804f, -0.9238795325f, -0.8314696123f,
    -0.7071067812f, -0.5555702330f, -0.3826834324f, -0.1950903220f,
    -0.0000000000f,  0.1950903220f,  0.3826834324f,  0.5555702330f,
     0.7071067812f,  0.8314696123f,  0.9238795325f,  0.9807852804f };
__device__ constexpr float SIN32[32] = {
     0.0000000000f,  0.1950903220f,  0.3826834324f,  0.5555702330f,
     0.7071067812f,  0.8314696123f,  0.9238795325f,  0.9807852804f,
     1.0000000000f,  0.9807852804f,  0.9238795325f,  0.8314696123f,
     0.7071067812f,  0.5555702330f,  0.3826834324f,  0.1950903220f,
     0.0000000000f, -0.1950903220f, -0.3826834324f, -0.5555702330f,
    -0.7071067812f, -0.8314696123f, -0.9238795325f, -0.9807852804f,
    -1.0000000000f, -0.9807852804f, -0.9238795325f, -0.8314696123f,
    -0.7071067812f, -0.5555702330f, -0.3826834324f, -0.1950903220f };

__device__ __forceinline__ unsigned short f2bf(float x) {
    unsigned int u = __float_as_uint(x);
    u += 0x7FFFu + ((u >> 16) & 1u);            // RNE
    return (unsigned short)(u >> 16);
}
__device__ __forceinline__ float bf2f(unsigned int h) {
    return __uint_as_float(h << 16);
}
__device__ __forceinline__ unsigned int pack2(float a, float b) {
    return (unsigned int)f2bf(a) | ((unsigned int)f2bf(b) << 16);
}
__device__ __forceinline__ unsigned char f2e4m3(float x) {
    __hip_fp8_e4m3 h(x);
    return (unsigned char)h.__x;
}
__device__ __forceinline__ float e4m3f(unsigned int b) {
    __hip_fp8_e4m3 h; h.__x = (__hip_fp8_storage_t)b;
    return (float)h;
}
__device__ __forceinline__ unsigned int pk4_e4m3(const float* v) {
    return (unsigned)f2e4m3(v[0]) | ((unsigned)f2e4m3(v[1]) << 8) |
           ((unsigned)f2e4m3(v[2]) << 16) | ((unsigned)f2e4m3(v[3]) << 24);
}

// ---------------- norm of wfft (closed form via Parseval) ----------------
__global__ void norm_part(const float* __restrict__ w, float* __restrict__ red) {
    int idx = blockIdx.x * 256 + threadIdx.x;
    const float* wp = w + (size_t)idx * 9;
    float s2 = 0.f, aa = 0.f, bb = 0.f;
#pragma unroll
    for (int u = 0; u < 3; u++) {
        float w0 = wp[u*3+0], w1 = wp[u*3+1], w2 = wp[u*3+2];
        s2 += w0*w0 + w1*w1 + w2*w2;
        float au = w0 + w1 + w2, bu = w0 - w1 + w2;
        aa += au*au; bb += bu*bu;
    }
    float p = 512.f*s2 + 16.f*(aa + bb);
    __shared__ float sm[256];
    sm[threadIdx.x] = p; __syncthreads();
    for (int s = 128; s > 0; s >>= 1) {
        if (threadIdx.x < s) sm[threadIdx.x] += sm[threadIdx.x + s];
        __syncthreads();
    }
    if (threadIdx.x == 0) red[blockIdx.x] = sm[0];
}

__global__ void norm_final(const float* __restrict__ red, const float* __restrict__ alpha,
                           float* __restrict__ sig) {
    __shared__ float sm[256];
    sm[threadIdx.x] = red[threadIdx.x]; __syncthreads();
    for (int s = 128; s > 0; s >>= 1) {
        if (threadIdx.x < s) sm[threadIdx.x] += sm[threadIdx.x + s];
        __syncthreads();
    }
    if (threadIdx.x == 0) sig[0] = alpha[0] / sqrtf(sm[0]);
}

// ---------------- H fragments (A-operand: m=o, k=c), bf16 ----------------
__global__ void hfrag_build(const float* __restrict__ H, unsigned short* __restrict__ Hfrag) {
    int kk = blockIdx.x, mt = blockIdx.y, lane = threadIdx.x;   // 64 threads
    int o = mt*16 + (lane & 15), c0 = kk*32 + (lane >> 4)*8;
    const float* hp = H + (size_t)o*NCH + c0;
    uint4 u;
    u.x = pack2(hp[0], hp[1]); u.y = pack2(hp[2], hp[3]);
    u.z = pack2(hp[4], hp[5]); u.w = pack2(hp[6], hp[7]);
    ((uint4*)Hfrag)[((size_t)kk*16 + mt)*64 + lane] = u;
}

// ---------------- rfft2: register-resident DFT, 8 tiles per 256-thread block ----------------
__global__ __launch_bounds__(256) void rfft2_reg(const float* __restrict__ x,
                                                 float2* __restrict__ tmp)
{
    __shared__ float2 T[8][544];       // [half][r*17+j], ~35 KB
    __shared__ float2 Z[8][544];       // output staging, ~35 KB
    __shared__ float wc[32], wsn[32];
    int t = threadIdx.x;
    int half = t >> 5, lane = t & 31;
    int cb = blockIdx.x * 8 + half;    // tile index in tmp order: cb = c*32 + b
    int c = cb >> 5, b = cb & 31;
    if (t < 32) { wc[t] = COS32[t]; wsn[t] = SIN32[t]; }
    float xr[32];
    const float* xp = x + ((size_t)(b * NCH + c)) * 1024 + lane * 32;
#pragma unroll
    for (int q = 0; q < 8; q++) {
        float4 v = *(const float4*)(xp + q*4);
        xr[q*4+0] = v.x; xr[q*4+1] = v.y; xr[q*4+2] = v.z; xr[q*4+3] = v.w;
    }
    float x0v = xr[0], x16v = xr[16];
    float es[15], os[15];
#pragma unroll
    for (int s = 1; s <= 15; s++) { es[s-1] = xr[s] + xr[32-s]; os[s-1] = xr[s] - xr[32-s]; }
#pragma unroll
    for (int j = 0; j < 17; j++) {
        float ax = x0v + ((j & 1) ? -x16v : x16v);
        float ay = 0.f;
#pragma unroll
        for (int s = 1; s <= 15; s++) {
            int m = (j * s) & 31;
            ax += es[s-1] * COS32[m];
            ay -= os[s-1] * SIN32[m];
        }
        T[half][lane*17 + j] = make_float2(ax, ay);
    }
    __syncthreads();
    float wr_[16], wi_[16];
#pragma unroll
    for (int r = 0; r < 16; r++) {
        int m = (lane * r) & 31;
        wr_[r] = wc[m]; wi_[r] = wsn[m];
    }
    float sgn = (lane & 1) ? -1.f : 1.f;    // (-1)^i
#pragma unroll
    for (int j = 0; j < 17; j++) {
        float ax = 0.f, ay = 0.f;
#pragma unroll
        for (int r = 0; r < 16; r++) {
            float2 t1 = T[half][r*17 + j];
            float2 t2 = T[half][(r+16)*17 + j];
            float ex = fmaf(sgn, t2.x, t1.x);
            float ey = fmaf(sgn, t2.y, t1.y);
            ax += ex * wr_[r] + ey * wi_[r];
            ay += ey * wr_[r] - ex * wi_[r];
        }
        Z[half][lane*17 + j] = make_float2(ax, ay);
    }
    __syncthreads();
    float2* outp = tmp + (size_t)blockIdx.x * 8 * 544;
    const float2* zf = (const float2*)Z;
#pragma unroll
    for (int u = 0; u < 17; u++)
        outp[u*256 + t] = zf[u*256 + t];
}

// ---------------- transpose tmp[cb][f] -> fp32 planes + fp8 planes [f][b][c] ----------------
__global__ __launch_bounds__(256) void transpose_z(const float2* __restrict__ tmp,
        float* __restrict__ z32r, float* __restrict__ z32i,
        unsigned char* __restrict__ z8r, unsigned char* __restrict__ z8i)
{
    __shared__ float2 tile[32][33];
    int ct = blockIdx.x, ft = blockIdx.y, b = blockIdx.z;
    int t = threadIdx.x;
#pragma unroll
    for (int it = 0; it < 4; it++) {
        int idx = t + it*256; int cl = idx >> 5, fl = idx & 31;
        tile[cl][fl] = tmp[((size_t)((ct*32 + cl)*32 + b))*544 + ft*32 + fl];
    }
    __syncthreads();
#pragma unroll
    for (int it = 0; it < 4; it++) {
        int idx = t + it*256; int fl = idx >> 5, cl = idx & 31;
        float2 v = tile[cl][fl];
        size_t zi_ = ((size_t)(ft*32 + fl)*NB + b)*NCH + ct*32 + cl;
        z32r[zi_] = v.x; z32i[zi_] = v.y;
        z8r[zi_] = f2e4m3(v.x); z8i[zi_] = f2e4m3(v.y);
    }
}

// ---------------- A-build, factorized + direct fragment writes ----------------
__global__ __launch_bounds__(256) void a_build_direct(const float* __restrict__ w,
        const float* __restrict__ sig, unsigned int* __restrict__ Afrag)
{
    int mt = blockIdx.x, kk = blockIdx.y, j = blockIdx.z;   // 16, 8, 17
    int t = threadIdx.x;
    int wv = t & 127;
    int c   = mt*16 + ((wv >> 1) & 15);
    int cp0 = kk*32 + (wv >> 5)*8 + (wv & 1)*4;
    bool isReal = (t < 128);
    float sS = sig[0] * ASCALE;
    float sgnS = isReal ? sS : -sS;
    f32x4 P1, P2, P3, P4, P5;
#pragma unroll
    for (int e = 0; e < 4; e++) {
        int cp = cp0 + e;
        const float* p1 = w + ((size_t)c*NCH + cp)*9;
        const float* p2 = w + ((size_t)cp*NCH + c)*9;
        float u_[9];
#pragma unroll
        for (int q = 0; q < 9; q++)
            u_[q] = isReal ? (p1[q] - p2[q]) : (p1[q] + p2[q]);
        if (isReal) {
            P1[e] = sgnS * u_[4];
            P2[e] = sgnS * (u_[3] + u_[5]);
            P3[e] = sgnS * (u_[1] + u_[7]);
            P4[e] = sgnS * (u_[0] + u_[2] + u_[6] + u_[8]);
            P5[e] = sgnS * ((u_[6] - u_[8]) - (u_[0] - u_[2]));
        } else {
            P1[e] = sgnS * (u_[3] - u_[5]);
            P2[e] = sgnS * ((u_[0] - u_[2]) + (u_[6] - u_[8]));
            P3[e] = sgnS * (u_[1] - u_[7]);
            P4[e] = sgnS * ((u_[0] + u_[2]) - (u_[6] + u_[8]));
            P5[e] = 0.f;
        }
    }
    float cps = COS32[j], sns = SIN32[j];
    f32x4 Aj, Bj, Cj;
    if (isReal) { Aj = P1 + cps*P2; Bj = P3 + cps*P4; Cj = sns*P5; }
    else        { Aj = sns*P1;      Bj = sns*P2;      Cj = P3 + cps*P4; }
    unsigned int* out = Afrag + ((size_t)j*128 + kk*16 + mt)*256 + t;
#pragma unroll
    for (int i = 0; i < 32; i++) {
        f32x4 v = Aj + COS32[i]*Bj + SIN32[i]*Cj;   // compile-time twiddles
        *out = (unsigned)f2e4m3(v[0]) | ((unsigned)f2e4m3(v[1]) << 8)
             | ((unsigned)f2e4m3(v[2]) << 16) | ((unsigned)f2e4m3(v[3]) << 24);
        out += (size_t)17*32768;   // fl = i*17 + j
    }
}

// ---------------- neum_fused: t = z - A z ; wx = z32 - 2 A t ; wxh = H wx ----------------
// A in registers across both fp8 matmuls. Barrier chain cut 5->3: t goes to its
// own LDS buffer (no WAR with mm1 reads of z / RAW handled by one barrier), and
// the mm2->epi2 barrier was redundant (disjoint LDS buffers).
__global__ __launch_bounds__(512) void neum_fused(
    const unsigned char* __restrict__ Afrag,
    const unsigned short* __restrict__ Hfrag,
    const unsigned char* __restrict__ z8r, const unsigned char* __restrict__ z8i,
    const float* __restrict__ z32r, const float* __restrict__ z32i,
    unsigned short* __restrict__ wxhR, unsigned short* __restrict__ wxhI)
{
    __shared__ uint2 lz8[2][1024];   // 16 KB: fp8 z
    __shared__ uint2 lt8[2][1024];   // 16 KB: fp8 t
    __shared__ uint4 lw[2][1024];    // 32 KB: bf16 wx
    int fl = blockIdx.x;
    int f = fl;
    int t = threadIdx.x;
    const uint2* s0 = (const uint2*)(z8r + (size_t)f*8192);
    const uint2* s1 = (const uint2*)(z8i + (size_t)f*8192);
    for (int u = t; u < 2048; u += 512) {
        int p = u >> 10, idx = u & 1023;
        int b = idx >> 5, o16 = idx & 31;
        lz8[p][b*32 + (o16 ^ (b & 7))] = (p ? s1 : s0)[idx];
    }
    int w = t >> 6, lane = t & 63, lo = lane & 15, hi = lane >> 4;
    const uint2* A8 = (const uint2*)Afrag;
    const uint4* H4 = (const uint4*)Hfrag;
    long arK[8][2], aiK[8][2];
#pragma unroll
    for (int kk = 0; kk < 8; kk++) {
#pragma unroll
        for (int mt = 0; mt < 2; mt++) {
            int mtg = w*2 + mt;
            size_t idx = (((size_t)fl*8 + kk)*16 + mtg)*128 + lane;
            arK[kk][mt] = __builtin_bit_cast(long, A8[idx]);
            aiK[kk][mt] = __builtin_bit_cast(long, A8[idx + 64]);
        }
    }
    __syncthreads();   // bar1: mm1 needs staged z
    f32x4 accr[2][2], acci[2][2];
    f32x4 zz = {0.f, 0.f, 0.f, 0.f};
#pragma unroll
    for (int mt = 0; mt < 2; mt++)
#pragma unroll
        for (int nt = 0; nt < 2; nt++) { accr[mt][nt] = zz; acci[mt][nt] = zz; }
    // ---- matmul 1: acc = A * z (fp8) ----
#pragma unroll
    for (int kk = 0; kk < 8; kk++) {
        long zr[2], zi_[2];
#pragma unroll
        for (int nt = 0; nt < 2; nt++) {
            int b = nt*16 + lo;
            int du = b*32 + ((kk*4 + hi) ^ (b & 7));
            zr[nt]  = __builtin_bit_cast(long, lz8[0][du]);
            zi_[nt] = __builtin_bit_cast(long, lz8[1][du]);
        }
#pragma unroll
        for (int mt = 0; mt < 2; mt++) {
            uint2 vb = __builtin_bit_cast(uint2, aiK[kk][mt]);
            long ain = __builtin_bit_cast(long, make_uint2(vb.x ^ 0x80808080u, vb.y ^ 0x80808080u));
#pragma unroll
            for (int nt = 0; nt < 2; nt++) {
                accr[mt][nt] = __builtin_amdgcn_mfma_f32_16x16x32_fp8_fp8(arK[kk][mt], zr[nt],  accr[mt][nt], 0, 0, 0);
                accr[mt][nt] = __builtin_amdgcn_mfma_f32_16x16x32_fp8_fp8(ain,        zi_[nt], accr[mt][nt], 0, 0, 0);
                acci[mt][nt] = __builtin_amdgcn_mfma_f32_16x16x32_fp8_fp8(arK[kk][mt], zi_[nt], acci[mt][nt], 0, 0, 0);
                acci[mt][nt] = __builtin_amdgcn_mfma_f32_16x16x32_fp8_fp8(aiK[kk][mt], zr[nt],  acci[mt][nt], 0, 0, 0);
            }
        }
    }
    // ---- epilogue 1 (no barrier: lz8 read-only here, t goes to lt8) ----
#pragma unroll
    for (int mt = 0; mt < 2; mt++)
#pragma unroll
        for (int nt = 0; nt < 2; nt++) {
            int c0 = w*32 + mt*16 + hi*4;
            int b  = nt*16 + lo;
            int duc = b*32 + ((c0 >> 3) ^ (b & 7));
            int sel = (c0 >> 2) & 1;
            uint2 q0 = lz8[0][duc], q1 = lz8[1][duc];
            unsigned qr = sel ? q0.y : q0.x;
            unsigned qi = sel ? q1.y : q1.x;
            float zfr[4] = { e4m3f(qr & 0xffu), e4m3f((qr>>8)&0xffu),
                             e4m3f((qr>>16)&0xffu), e4m3f(qr>>24) };
            float zfi[4] = { e4m3f(qi & 0xffu), e4m3f((qi>>8)&0xffu),
                             e4m3f((qi>>16)&0xffu), e4m3f(qi>>24) };
            float vr[4], vi[4];
#pragma unroll
            for (int jj = 0; jj < 4; jj++) {
                vr[jj] = zfr[jj] - accr[mt][nt][jj] * INV_ASCALE;
                vi[jj] = zfi[jj] - acci[mt][nt][jj] * INV_ASCALE;
            }
            ((unsigned int*)&lt8[0][duc])[sel] = pk4_e4m3(vr);
            ((unsigned int*)&lt8[1][duc])[sel] = pk4_e4m3(vi);
        }
    __syncthreads();   // bar2: mm2 needs all t writes
    // ---- matmul 2: acc = A * t (A from registers) ----
#pragma unroll
    for (int mt = 0; mt < 2; mt++)
#pragma unroll
        for (int nt = 0; nt < 2; nt++) { accr[mt][nt] = zz; acci[mt][nt] = zz; }
#pragma unroll
    for (int kk = 0; kk < 8; kk++) {
        long zr[2], zi_[2];
#pragma unroll
        for (int nt = 0; nt < 2; nt++) {
            int b = nt*16 + lo;
            int du = b*32 + ((kk*4 + hi) ^ (b & 7));
            zr[nt]  = __builtin_bit_cast(long, lt8[0][du]);
            zi_[nt] = __builtin_bit_cast(long, lt8[1][du]);
        }
#pragma unroll
        for (int mt = 0; mt < 2; mt++) {
            uint2 vb = __builtin_bit_cast(uint2, aiK[kk][mt]);
            long ain = __builtin_bit_cast(long, make_uint2(vb.x ^ 0x80808080u, vb.y ^ 0x80808080u));
#pragma unroll
            for (int nt = 0; nt < 2; nt++) {
                accr[mt][nt] = __builtin_amdgcn_mfma_f32_16x16x32_fp8_fp8(arK[kk][mt], zr[nt],  accr[mt][nt], 0, 0, 0);
                accr[mt][nt] = __builtin_amdgcn_mfma_f32_16x16x32_fp8_fp8(ain,        zi_[nt], accr[mt][nt], 0, 0, 0);
                acci[mt][nt] = __builtin_amdgcn_mfma_f32_16x16x32_fp8_fp8(arK[kk][mt], zi_[nt], acci[mt][nt], 0, 0, 0);
                acci[mt][nt] = __builtin_amdgcn_mfma_f32_16x16x32_fp8_fp8(aiK[kk][mt], zr[nt],  acci[mt][nt], 0, 0, 0);
            }
        }
    }
    // ---- epilogue 2 (no barrier: mm2 reads lt8, we write lw — disjoint) ----
#pragma unroll
    for (int mt = 0; mt < 2; mt++)
#pragma unroll
        for (int nt = 0; nt < 2; nt++) {
            int c0 = w*32 + mt*16 + hi*4;
            int b  = nt*16 + lo;
            size_t zb = ((size_t)f*NB + b)*NCH + c0;
            float4 z4r = *(const float4*)(z32r + zb);
            float4 z4i = *(const float4*)(z32i + zb);
            const float k2 = 2.f * INV_ASCALE;
            float vr[4] = { z4r.x - k2*accr[mt][nt][0], z4r.y - k2*accr[mt][nt][1],
                            z4r.z - k2*accr[mt][nt][2], z4r.w - k2*accr[mt][nt][3] };
            float vi[4] = { z4i.x - k2*acci[mt][nt][0], z4i.y - k2*acci[mt][nt][1],
                            z4i.z - k2*acci[mt][nt][2], z4i.w - k2*acci[mt][nt][3] };
            int o16c = c0 >> 3;
            int duc = b*32 + (o16c ^ (b & 7));
            int sel = (c0 >> 2) & 1;
            ((uint2*)&lw[0][duc])[sel] = make_uint2(pack2(vr[0], vr[1]), pack2(vr[2], vr[3]));
            ((uint2*)&lw[1][duc])[sel] = make_uint2(pack2(vi[0], vi[1]), pack2(vi[2], vi[3]));
        }
    __syncthreads();   // bar3: mm3 needs all wx writes
    // ---- matmul 3: wxh = H * wx (bf16) ----
#pragma unroll
    for (int mt = 0; mt < 2; mt++)
#pragma unroll
        for (int nt = 0; nt < 2; nt++) { accr[mt][nt] = zz; acci[mt][nt] = zz; }
#pragma unroll
    for (int kk = 0; kk < 8; kk++) {
        bf16x8 hm[2];
#pragma unroll
        for (int mt = 0; mt < 2; mt++) {
            int mtg = w*2 + mt;
            hm[mt] = __builtin_bit_cast(bf16x8, H4[((size_t)kk*16 + mtg)*64 + lane]);
        }
        bf16x8 zr[2], zi_[2];
#pragma unroll
        for (int nt = 0; nt < 2; nt++) {
            int b = nt*16 + lo;
            int du = b*32 + ((kk*4 + hi) ^ (b & 7));
            zr[nt]  = __builtin_bit_cast(bf16x8, lw[0][du]);
            zi_[nt] = __builtin_bit_cast(bf16x8, lw[1][du]);
        }
#pragma unroll
        for (int mt = 0; mt < 2; mt++)
#pragma unroll
            for (int nt = 0; nt < 2; nt++) {
                accr[mt][nt] = __builtin_amdgcn_mfma_f32_16x16x32_bf16(hm[mt], zr[nt],  accr[mt][nt], 0, 0, 0);
                acci[mt][nt] = __builtin_amdgcn_mfma_f32_16x16x32_bf16(hm[mt], zi_[nt], acci[mt][nt], 0, 0, 0);
            }
    }
    // ---- epilogue 3: wxh bf16 planes, [f][b][o] layout ----
#pragma unroll
    for (int mt = 0; mt < 2; mt++)
#pragma unroll
        for (int nt = 0; nt < 2; nt++) {
            int o0 = w*32 + mt*16 + hi*4;
            int b  = nt*16 + lo;
            size_t zb = ((size_t)f*NB + b)*NCH + o0;
            *(uint2*)(wxhR + zb) = make_uint2(pack2(accr[mt][nt][0], accr[mt][nt][1]),
                                              pack2(accr[mt][nt][2], accr[mt][nt][3]));
            *(uint2*)(wxhI + zb) = make_uint2(pack2(acci[mt][nt][0], acci[mt][nt][1]),
                                              pack2(acci[mt][nt][2], acci[mt][nt][3]));
        }
}

// ---------------- pass I: complex ifft along i -> G[j][r][ob] (coalesced stores) ----------------
template<int RH>
__device__ __forceinline__ void ifft_i_body(const unsigned short* __restrict__ YR,
                                            const unsigned short* __restrict__ YI,
                                            float2* __restrict__ G, int j, int ob)
{
    float2 Gacc[16];
#pragma unroll
    for (int rr = 0; rr < 16; rr++) Gacc[rr] = make_float2(0.f, 0.f);
#pragma unroll
    for (int i = 0; i < 32; i++) {
        size_t yi_ = (size_t)(i * 17 + j) * 8192 + ob;
        float Yx = bf2f(YR[yi_]);
        float Yy = bf2f(YI[yi_]);
#pragma unroll
        for (int rr = 0; rr < 16; rr++) {
            int m = (i * (RH * 16 + rr)) & 31;     // compile-time constant
            Gacc[rr].x += Yx*COS32[m] - Yy*SIN32[m];
            Gacc[rr].y += Yx*SIN32[m] + Yy*COS32[m];
        }
    }
#pragma unroll
    for (int rr = 0; rr < 16; rr++) {
        G[((size_t)(j*32 + RH*16 + rr))*8192 + ob] =
            make_float2(Gacc[rr].x * (1.f/32.f), Gacc[rr].y * (1.f/32.f));
    }
}

__global__ __launch_bounds__(256) void ifft_i(const unsigned short* __restrict__ YR,
                                              const unsigned short* __restrict__ YI,
                                              float2* __restrict__ G) {
    int bid = blockIdx.x;
    int j   = bid >> 6;          // 0..16
    int rh  = (bid >> 5) & 1;    // 0..1
    int obc = bid & 31;          // 0..31
    int ob  = obc * 256 + threadIdx.x;
    if (rh == 0) ifft_i_body<0>(YR, YI, G, j, ob);
    else         ifft_i_body<1>(YR, YI, G, j, ob);
}

// ---------------- pass II: irfft along j + bias -> out[b][o][r][s] ----------------
// ob = b*256 + o (plane layout [f][b][o])
__global__ __launch_bounds__(256) void irfft_j(const float2* __restrict__ G,
                                               const float* __restrict__ bias,
                                               float* __restrict__ out) {
    int gid = blockIdx.x * 256 + threadIdx.x;
    int r = gid >> 13, ob = gid & 8191;
    int b = ob >> 8, o = ob & 255;
    float2 Gv[17];
#pragma unroll
    for (int jj = 0; jj < 17; jj++)
        Gv[jj] = G[((size_t)(jj*32 + r))*8192 + ob];
    float y[32];
    float g0 = Gv[0].x, g16 = Gv[16].x;
#pragma unroll
    for (int s = 0; s < 32; s++) y[s] = g0 + ((s & 1) ? -g16 : g16);
#pragma unroll
    for (int jj = 1; jj < 16; jj++) {
#pragma unroll
        for (int s = 0; s < 32; s++) {
            int m = (jj * s) & 31;                 // compile-time constant
            y[s] += 2.f * (Gv[jj].x * COS32[m] - Gv[jj].y * SIN32[m]);
        }
    }
    float bv = bias[o];
    float* op = out + ((size_t)(b * NCH + o) * 32 + r) * 32;
#pragma unroll
    for (int s = 0; s < 32; s++) op[s] = y[s] * (1.f/32.f) + bv;
}

extern "C" void kernel_launch(void* const* d_in, const int* in_sizes, int n_in,
                              void* d_out, int out_size, void* d_ws, size_t ws_size,
                              hipStream_t stream) {
    (void)in_sizes; (void)n_in; (void)out_size;
    if (ws_size < WS_NEED) return;

    const float* x     = (const float*)d_in[0];
    const float* w     = (const float*)d_in[1];
    const float* alpha = (const float*)d_in[2];
    const float* H     = (const float*)d_in[3];
    const float* bias  = (const float*)d_in[4];
    float* out = (float*)d_out;

    char* ws = (char*)d_ws;
    unsigned char* Afrag = (unsigned char*)(ws + OFF_AFRAG);
    float2* tmp = (float2*)(ws + OFF_AFRAG);   // dead before a_build writes Afrag
    float2* G   = (float2*)(ws + OFF_AFRAG);   // live after neum pass (Afrag dead)
    unsigned char* z8r  = (unsigned char*)(ws + OFF_Z8R);
    unsigned char* z8i  = (unsigned char*)(ws + OFF_Z8I);
    float* z32r = (float*)(ws + OFF_Z32R);
    float* z32i = (float*)(ws + OFF_Z32I);
    unsigned short* wxhR = (unsigned short*)(ws + OFF_WXHR);
    unsigned short* wxhI = (unsigned short*)(ws + OFF_WXHI);
    unsigned short* Hfrag = (unsigned short*)(ws + OFF_HFRAG);
    float* red = (float*)(ws + OFF_RED);
    float* sig = red + 256;

    norm_part<<<256, 256, 0, stream>>>(w, red);
    norm_final<<<1, 256, 0, stream>>>(red, alpha, sig);
    hfrag_build<<<dim3(8, 16), 64, 0, stream>>>(H, Hfrag);

    rfft2_reg<<<1024, 256, 0, stream>>>(x, tmp);
    transpose_z<<<dim3(8, 17, 32), 256, 0, stream>>>(tmp, z32r, z32i, z8r, z8i);

    a_build_direct<<<dim3(16, 8, 17), 256, 0, stream>>>(w, sig, (unsigned int*)Afrag);
    neum_fused<<<NF, 512, 0, stream>>>(Afrag, Hfrag, z8r, z8i, z32r, z32i, wxhR, wxhI);

    ifft_i<<<1088, 256, 0, stream>>>(wxhR, wxhI, G);
    irfft_j<<<1024, 256, 0, stream>>>(G, bias, out);
}

// Round 19
// 168.378 us; speedup vs baseline: 1.2214x; 1.0022x over previous
//
#include <hip/hip_runtime.h>
#include <hip/hip_fp8.h>
#include <cstddef>

#define PI_F 3.14159265358979323846f

#define NCH 256   // C
#define NB  32    // B
#define NF  544   // n*(n/2+1),  f = i*17 + j

#define ASCALE     65536.0f
#define INV_ASCALE (1.0f/65536.0f)

typedef short  bf16x8 __attribute__((ext_vector_type(8)));
typedef float  f32x4  __attribute__((ext_vector_type(4)));

// ---- workspace layout (bytes), single-chunk, fp8 A ----
#define SZ_AFRAG ((size_t)NF*8*16*1024)         // 71,303,168 (fp8 fragments; tmp & G alias)
#define SZ_P8    ((size_t)NF*NB*NCH)            // 4,456,448  (fp8 plane)
#define SZ_PB    ((size_t)NF*NB*NCH*2)          // 8,912,896  (bf16 plane)
#define SZ_P32   ((size_t)NF*NB*NCH*4)          // 17,825,792 (fp32 plane)
#define OFF_AFRAG ((size_t)0)
#define OFF_Z8R  (OFF_AFRAG + SZ_AFRAG)
#define OFF_Z8I  (OFF_Z8R + SZ_P8)
#define OFF_Z32R (OFF_Z8I + SZ_P8)
#define OFF_Z32I (OFF_Z32R + SZ_P32)
#define OFF_WXHR (OFF_Z32I + SZ_P32)
#define OFF_WXHI (OFF_WXHR + SZ_PB)
#define OFF_HFRAG (OFF_WXHI + SZ_PB)
#define SZ_HFRAG ((size_t)8*16*1024)            // 131,072
#define OFF_RED  (OFF_HFRAG + SZ_HFRAG)
#define WS_NEED  (OFF_RED + (size_t)4096)       // ~134 MB

// 32-point twiddle tables: COS32[k]=cos(2pi k/32), SIN32[k]=sin(2pi k/32)
__device__ constexpr float COS32[32] = {
     1.0000000000f,  0.9807852804f,  0.9238795325f,  0.8314696123f,
     0.7071067812f,  0.5555702330f,  0.3826834324f,  0.1950903220f,
     0.0000000000f, -0.1950903220f, -0.3826834324f, -0.5555702330f,
    -0.7071067812f, -0.8314696123f, -0.9238795325f, -0.9807852804f,
    -1.0000000000f, -0.9807852804f, -0.9238795325f, -0.8314696123f,
    -0.7071067812f, -0.5555702330f, -0.3826834324f, -0.1950903220f,
    -0.0000000000f,  0.1950903220f,  0.3826834324f,  0.5555702330f,
     0.7071067812f,  0.8314696123f,  0.9238795325f,  0.9807852804f };
__device__ constexpr float SIN32[32] = {
     0.0000000000f,  0.1950903220f,  0.3826834324f,  0.5555702330f,
     0.7071067812f,  0.8314696123f,  0.9238795325f,  0.9807852804f,
     1.0000000000f,  0.9807852804f,  0.9238795325f,  0.8314696123f,
     0.7071067812f,  0.5555702330f,  0.3826834324f,  0.1950903220f,
     0.0000000000f, -0.1950903220f, -0.3826834324f, -0.5555702330f,
    -0.7071067812f, -0.8314696123f, -0.9238795325f, -0.9807852804f,
    -1.0000000000f, -0.9807852804f, -0.9238795325f, -0.8314696123f,
    -0.7071067812f, -0.5555702330f, -0.3826834324f, -0.1950903220f };

__device__ __forceinline__ unsigned short f2bf(float x) {
    unsigned int u = __float_as_uint(x);
    u += 0x7FFFu + ((u >> 16) & 1u);            // RNE
    return (unsigned short)(u >> 16);
}
__device__ __forceinline__ float bf2f(unsigned int h) {
    return __uint_as_float(h << 16);
}
__device__ __forceinline__ unsigned int pack2(float a, float b) {
    return (unsigned int)f2bf(a) | ((unsigned int)f2bf(b) << 16);
}
__device__ __forceinline__ unsigned char f2e4m3(float x) {
    __hip_fp8_e4m3 h(x);
    return (unsigned char)h.__x;
}
__device__ __forceinline__ float e4m3f(unsigned int b) {
    __hip_fp8_e4m3 h; h.__x = (__hip_fp8_storage_t)b;
    return (float)h;
}
__device__ __forceinline__ unsigned int pk4_e4m3(const float* v) {
    return (unsigned)f2e4m3(v[0]) | ((unsigned)f2e4m3(v[1]) << 8) |
           ((unsigned)f2e4m3(v[2]) << 16) | ((unsigned)f2e4m3(v[3]) << 24);
}

// ---------------- norm of wfft (closed form via Parseval) ----------------
__global__ void norm_part(const float* __restrict__ w, float* __restrict__ red) {
    int idx = blockIdx.x * 256 + threadIdx.x;
    const float* wp = w + (size_t)idx * 9;
    float s2 = 0.f, aa = 0.f, bb = 0.f;
#pragma unroll
    for (int u = 0; u < 3; u++) {
        float w0 = wp[u*3+0], w1 = wp[u*3+1], w2 = wp[u*3+2];
        s2 += w0*w0 + w1*w1 + w2*w2;
        float au = w0 + w1 + w2, bu = w0 - w1 + w2;
        aa += au*au; bb += bu*bu;
    }
    float p = 512.f*s2 + 16.f*(aa + bb);
    __shared__ float sm[256];
    sm[threadIdx.x] = p; __syncthreads();
    for (int s = 128; s > 0; s >>= 1) {
        if (threadIdx.x < s) sm[threadIdx.x] += sm[threadIdx.x + s];
        __syncthreads();
    }
    if (threadIdx.x == 0) red[blockIdx.x] = sm[0];
}

__global__ void norm_final(const float* __restrict__ red, const float* __restrict__ alpha,
                           float* __restrict__ sig) {
    __shared__ float sm[256];
    sm[threadIdx.x] = red[threadIdx.x]; __syncthreads();
    for (int s = 128; s > 0; s >>= 1) {
        if (threadIdx.x < s) sm[threadIdx.x] += sm[threadIdx.x + s];
        __syncthreads();
    }
    if (threadIdx.x == 0) sig[0] = alpha[0] / sqrtf(sm[0]);
}

// ---------------- H fragments (A-operand: m=o, k=c), bf16 ----------------
__global__ void hfrag_build(const float* __restrict__ H, unsigned short* __restrict__ Hfrag) {
    int kk = blockIdx.x, mt = blockIdx.y, lane = threadIdx.x;   // 64 threads
    int o = mt*16 + (lane & 15), c0 = kk*32 + (lane >> 4)*8;
    const float* hp = H + (size_t)o*NCH + c0;
    uint4 u;
    u.x = pack2(hp[0], hp[1]); u.y = pack2(hp[2], hp[3]);
    u.z = pack2(hp[4], hp[5]); u.w = pack2(hp[6], hp[7]);
    ((uint4*)Hfrag)[((size_t)kk*16 + mt)*64 + lane] = u;
}

// ---------------- rfft2: register-resident DFT, 8 tiles per 256-thread block ----------------
__global__ __launch_bounds__(256) void rfft2_reg(const float* __restrict__ x,
                                                 float2* __restrict__ tmp)
{
    __shared__ float2 T[8][544];       // [half][r*17+j], ~35 KB
    __shared__ float2 Z[8][544];       // output staging, ~35 KB
    __shared__ float wc[32], wsn[32];
    int t = threadIdx.x;
    int half = t >> 5, lane = t & 31;
    int cb = blockIdx.x * 8 + half;    // tile index in tmp order: cb = c*32 + b
    int c = cb >> 5, b = cb & 31;
    if (t < 32) { wc[t] = COS32[t]; wsn[t] = SIN32[t]; }
    float xr[32];
    const float* xp = x + ((size_t)(b * NCH + c)) * 1024 + lane * 32;
#pragma unroll
    for (int q = 0; q < 8; q++) {
        float4 v = *(const float4*)(xp + q*4);
        xr[q*4+0] = v.x; xr[q*4+1] = v.y; xr[q*4+2] = v.z; xr[q*4+3] = v.w;
    }
    float x0v = xr[0], x16v = xr[16];
    float es[15], os[15];
#pragma unroll
    for (int s = 1; s <= 15; s++) { es[s-1] = xr[s] + xr[32-s]; os[s-1] = xr[s] - xr[32-s]; }
#pragma unroll
    for (int j = 0; j < 17; j++) {
        float ax = x0v + ((j & 1) ? -x16v : x16v);
        float ay = 0.f;
#pragma unroll
        for (int s = 1; s <= 15; s++) {
            int m = (j * s) & 31;
            ax += es[s-1] * COS32[m];
            ay -= os[s-1] * SIN32[m];
        }
        T[half][lane*17 + j] = make_float2(ax, ay);
    }
    __syncthreads();
    float wr_[16], wi_[16];
#pragma unroll
    for (int r = 0; r < 16; r++) {
        int m = (lane * r) & 31;
        wr_[r] = wc[m]; wi_[r] = wsn[m];
    }
    float sgn = (lane & 1) ? -1.f : 1.f;    // (-1)^i
#pragma unroll
    for (int j = 0; j < 17; j++) {
        float ax = 0.f, ay = 0.f;
#pragma unroll
        for (int r = 0; r < 16; r++) {
            float2 t1 = T[half][r*17 + j];
            float2 t2 = T[half][(r+16)*17 + j];
            float ex = fmaf(sgn, t2.x, t1.x);
            float ey = fmaf(sgn, t2.y, t1.y);
            ax += ex * wr_[r] + ey * wi_[r];
            ay += ey * wr_[r] - ex * wi_[r];
        }
        Z[half][lane*17 + j] = make_float2(ax, ay);
    }
    __syncthreads();
    float2* outp = tmp + (size_t)blockIdx.x * 8 * 544;
    const float2* zf = (const float2*)Z;
#pragma unroll
    for (int u = 0; u < 17; u++)
        outp[u*256 + t] = zf[u*256 + t];
}

// ---------------- transpose tmp[cb][f] -> fp32 planes + fp8 planes [f][b][c] ----------------
__global__ __launch_bounds__(256) void transpose_z(const float2* __restrict__ tmp,
        float* __restrict__ z32r, float* __restrict__ z32i,
        unsigned char* __restrict__ z8r, unsigned char* __restrict__ z8i)
{
    __shared__ float2 tile[32][33];
    int ct = blockIdx.x, ft = blockIdx.y, b = blockIdx.z;
    int t = threadIdx.x;
#pragma unroll
    for (int it = 0; it < 4; it++) {
        int idx = t + it*256; int cl = idx >> 5, fl = idx & 31;
        tile[cl][fl] = tmp[((size_t)((ct*32 + cl)*32 + b))*544 + ft*32 + fl];
    }
    __syncthreads();
#pragma unroll
    for (int it = 0; it < 4; it++) {
        int idx = t + it*256; int fl = idx >> 5, cl = idx & 31;
        float2 v = tile[cl][fl];
        size_t zi_ = ((size_t)(ft*32 + fl)*NB + b)*NCH + ct*32 + cl;
        z32r[zi_] = v.x; z32i[zi_] = v.y;
        z8r[zi_] = f2e4m3(v.x); z8i[zi_] = f2e4m3(v.y);
    }
}

// ---------------- A-build, factorized + direct fragment writes ----------------
__global__ __launch_bounds__(256) void a_build_direct(const float* __restrict__ w,
        const float* __restrict__ sig, unsigned int* __restrict__ Afrag)
{
    int mt = blockIdx.x, kk = blockIdx.y, j = blockIdx.z;   // 16, 8, 17
    int t = threadIdx.x;
    int wv = t & 127;
    int c   = mt*16 + ((wv >> 1) & 15);
    int cp0 = kk*32 + (wv >> 5)*8 + (wv & 1)*4;
    bool isReal = (t < 128);
    float sS = sig[0] * ASCALE;
    float sgnS = isReal ? sS : -sS;
    f32x4 P1, P2, P3, P4, P5;
#pragma unroll
    for (int e = 0; e < 4; e++) {
        int cp = cp0 + e;
        const float* p1 = w + ((size_t)c*NCH + cp)*9;
        const float* p2 = w + ((size_t)cp*NCH + c)*9;
        float u_[9];
#pragma unroll
        for (int q = 0; q < 9; q++)
            u_[q] = isReal ? (p1[q] - p2[q]) : (p1[q] + p2[q]);
        if (isReal) {
            P1[e] = sgnS * u_[4];
            P2[e] = sgnS * (u_[3] + u_[5]);
            P3[e] = sgnS * (u_[1] + u_[7]);
            P4[e] = sgnS * (u_[0] + u_[2] + u_[6] + u_[8]);
            P5[e] = sgnS * ((u_[6] - u_[8]) - (u_[0] - u_[2]));
        } else {
            P1[e] = sgnS * (u_[3] - u_[5]);
            P2[e] = sgnS * ((u_[0] - u_[2]) + (u_[6] - u_[8]));
            P3[e] = sgnS * (u_[1] - u_[7]);
            P4[e] = sgnS * ((u_[0] + u_[2]) - (u_[6] + u_[8]));
            P5[e] = 0.f;
        }
    }
    float cps = COS32[j], sns = SIN32[j];
    f32x4 Aj, Bj, Cj;
    if (isReal) { Aj = P1 + cps*P2; Bj = P3 + cps*P4; Cj = sns*P5; }
    else        { Aj = sns*P1;      Bj = sns*P2;      Cj = P3 + cps*P4; }
    unsigned int* out = Afrag + ((size_t)j*128 + kk*16 + mt)*256 + t;
#pragma unroll
    for (int i = 0; i < 32; i++) {
        f32x4 v = Aj + COS32[i]*Bj + SIN32[i]*Cj;   // compile-time twiddles
        *out = (unsigned)f2e4m3(v[0]) | ((unsigned)f2e4m3(v[1]) << 8)
             | ((unsigned)f2e4m3(v[2]) << 16) | ((unsigned)f2e4m3(v[3]) << 24);
        out += (size_t)17*32768;   // fl = i*17 + j
    }
}

// ---------------- neum_fused: t = z - A z ; wx = z32 - 2 A t ; wxh = H wx ----------------
// A in registers; 3 barriers; LDS swizzle widened ^(b&7) -> ^(b&15):
// uint2 (8B) reads were 8-way bank conflicts (b*32*8 vanishes mod 32 banks),
// now 4-way; uint4 lw reads drop 8-way -> 2-way (free).
__global__ __launch_bounds__(512) void neum_fused(
    const unsigned char* __restrict__ Afrag,
    const unsigned short* __restrict__ Hfrag,
    const unsigned char* __restrict__ z8r, const unsigned char* __restrict__ z8i,
    const float* __restrict__ z32r, const float* __restrict__ z32i,
    unsigned short* __restrict__ wxhR, unsigned short* __restrict__ wxhI)
{
    __shared__ uint2 lz8[2][1024];   // 16 KB: fp8 z
    __shared__ uint2 lt8[2][1024];   // 16 KB: fp8 t
    __shared__ uint4 lw[2][1024];    // 32 KB: bf16 wx
    int fl = blockIdx.x;
    int f = fl;
    int t = threadIdx.x;
    const uint2* s0 = (const uint2*)(z8r + (size_t)f*8192);
    const uint2* s1 = (const uint2*)(z8i + (size_t)f*8192);
    for (int u = t; u < 2048; u += 512) {
        int p = u >> 10, idx = u & 1023;
        int b = idx >> 5, o16 = idx & 31;
        lz8[p][b*32 + (o16 ^ (b & 15))] = (p ? s1 : s0)[idx];
    }
    int w = t >> 6, lane = t & 63, lo = lane & 15, hi = lane >> 4;
    const uint2* A8 = (const uint2*)Afrag;
    const uint4* H4 = (const uint4*)Hfrag;
    long arK[8][2], aiK[8][2];
#pragma unroll
    for (int kk = 0; kk < 8; kk++) {
#pragma unroll
        for (int mt = 0; mt < 2; mt++) {
            int mtg = w*2 + mt;
            size_t idx = (((size_t)fl*8 + kk)*16 + mtg)*128 + lane;
            arK[kk][mt] = __builtin_bit_cast(long, A8[idx]);
            aiK[kk][mt] = __builtin_bit_cast(long, A8[idx + 64]);
        }
    }
    __syncthreads();   // bar1: mm1 needs staged z
    f32x4 accr[2][2], acci[2][2];
    f32x4 zz = {0.f, 0.f, 0.f, 0.f};
#pragma unroll
    for (int mt = 0; mt < 2; mt++)
#pragma unroll
        for (int nt = 0; nt < 2; nt++) { accr[mt][nt] = zz; acci[mt][nt] = zz; }
    // ---- matmul 1: acc = A * z (fp8) ----
#pragma unroll
    for (int kk = 0; kk < 8; kk++) {
        long zr[2], zi_[2];
#pragma unroll
        for (int nt = 0; nt < 2; nt++) {
            int b = nt*16 + lo;
            int du = b*32 + ((kk*4 + hi) ^ (b & 15));
            zr[nt]  = __builtin_bit_cast(long, lz8[0][du]);
            zi_[nt] = __builtin_bit_cast(long, lz8[1][du]);
        }
#pragma unroll
        for (int mt = 0; mt < 2; mt++) {
            uint2 vb = __builtin_bit_cast(uint2, aiK[kk][mt]);
            long ain = __builtin_bit_cast(long, make_uint2(vb.x ^ 0x80808080u, vb.y ^ 0x80808080u));
#pragma unroll
            for (int nt = 0; nt < 2; nt++) {
                accr[mt][nt] = __builtin_amdgcn_mfma_f32_16x16x32_fp8_fp8(arK[kk][mt], zr[nt],  accr[mt][nt], 0, 0, 0);
                accr[mt][nt] = __builtin_amdgcn_mfma_f32_16x16x32_fp8_fp8(ain,        zi_[nt], accr[mt][nt], 0, 0, 0);
                acci[mt][nt] = __builtin_amdgcn_mfma_f32_16x16x32_fp8_fp8(arK[kk][mt], zi_[nt], acci[mt][nt], 0, 0, 0);
                acci[mt][nt] = __builtin_amdgcn_mfma_f32_16x16x32_fp8_fp8(aiK[kk][mt], zr[nt],  acci[mt][nt], 0, 0, 0);
            }
        }
    }
    // ---- epilogue 1 (no barrier: lz8 read-only here, t goes to lt8) ----
#pragma unroll
    for (int mt = 0; mt < 2; mt++)
#pragma unroll
        for (int nt = 0; nt < 2; nt++) {
            int c0 = w*32 + mt*16 + hi*4;
            int b  = nt*16 + lo;
            int duc = b*32 + ((c0 >> 3) ^ (b & 15));
            int sel = (c0 >> 2) & 1;
            uint2 q0 = lz8[0][duc], q1 = lz8[1][duc];
            unsigned qr = sel ? q0.y : q0.x;
            unsigned qi = sel ? q1.y : q1.x;
            float zfr[4] = { e4m3f(qr & 0xffu), e4m3f((qr>>8)&0xffu),
                             e4m3f((qr>>16)&0xffu), e4m3f(qr>>24) };
            float zfi[4] = { e4m3f(qi & 0xffu), e4m3f((qi>>8)&0xffu),
                             e4m3f((qi>>16)&0xffu), e4m3f(qi>>24) };
            float vr[4], vi[4];
#pragma unroll
            for (int jj = 0; jj < 4; jj++) {
                vr[jj] = zfr[jj] - accr[mt][nt][jj] * INV_ASCALE;
                vi[jj] = zfi[jj] - acci[mt][nt][jj] * INV_ASCALE;
            }
            ((unsigned int*)&lt8[0][duc])[sel] = pk4_e4m3(vr);
            ((unsigned int*)&lt8[1][duc])[sel] = pk4_e4m3(vi);
        }
    __syncthreads();   // bar2: mm2 needs all t writes
    // ---- matmul 2: acc = A * t (A from registers) ----
#pragma unroll
    for (int mt = 0; mt < 2; mt++)
#pragma unroll
        for (int nt = 0; nt < 2; nt++) { accr[mt][nt] = zz; acci[mt][nt] = zz; }
#pragma unroll
    for (int kk = 0; kk < 8; kk++) {
        long zr[2], zi_[2];
#pragma unroll
        for (int nt = 0; nt < 2; nt++) {
            int b = nt*16 + lo;
            int du = b*32 + ((kk*4 + hi) ^ (b & 15));
            zr[nt]  = __builtin_bit_cast(long, lt8[0][du]);
            zi_[nt] = __builtin_bit_cast(long, lt8[1][du]);
        }
#pragma unroll
        for (int mt = 0; mt < 2; mt++) {
            uint2 vb = __builtin_bit_cast(uint2, aiK[kk][mt]);
            long ain = __builtin_bit_cast(long, make_uint2(vb.x ^ 0x80808080u, vb.y ^ 0x80808080u));
#pragma unroll
            for (int nt = 0; nt < 2; nt++) {
                accr[mt][nt] = __builtin_amdgcn_mfma_f32_16x16x32_fp8_fp8(arK[kk][mt], zr[nt],  accr[mt][nt], 0, 0, 0);
                accr[mt][nt] = __builtin_amdgcn_mfma_f32_16x16x32_fp8_fp8(ain,        zi_[nt], accr[mt][nt], 0, 0, 0);
                acci[mt][nt] = __builtin_amdgcn_mfma_f32_16x16x32_fp8_fp8(arK[kk][mt], zi_[nt], acci[mt][nt], 0, 0, 0);
                acci[mt][nt] = __builtin_amdgcn_mfma_f32_16x16x32_fp8_fp8(aiK[kk][mt], zr[nt],  acci[mt][nt], 0, 0, 0);
            }
        }
    }
    // ---- epilogue 2 (no barrier: mm2 reads lt8, we write lw — disjoint) ----
#pragma unroll
    for (int mt = 0; mt < 2; mt++)
#pragma unroll
        for (int nt = 0; nt < 2; nt++) {
            int c0 = w*32 + mt*16 + hi*4;
            int b  = nt*16 + lo;
            size_t zb = ((size_t)f*NB + b)*NCH + c0;
            float4 z4r = *(const float4*)(z32r + zb);
            float4 z4i = *(const float4*)(z32i + zb);
            const float k2 = 2.f * INV_ASCALE;
            float vr[4] = { z4r.x - k2*accr[mt][nt][0], z4r.y - k2*accr[mt][nt][1],
                            z4r.z - k2*accr[mt][nt][2], z4r.w - k2*accr[mt][nt][3] };
            float vi[4] = { z4i.x - k2*acci[mt][nt][0], z4i.y - k2*acci[mt][nt][1],
                            z4i.z - k2*acci[mt][nt][2], z4i.w - k2*acci[mt][nt][3] };
            int o16c = c0 >> 3;
            int duc = b*32 + (o16c ^ (b & 15));
            int sel = (c0 >> 2) & 1;
            ((uint2*)&lw[0][duc])[sel] = make_uint2(pack2(vr[0], vr[1]), pack2(vr[2], vr[3]));
            ((uint2*)&lw[1][duc])[sel] = make_uint2(pack2(vi[0], vi[1]), pack2(vi[2], vi[3]));
        }
    __syncthreads();   // bar3: mm3 needs all wx writes
    // ---- matmul 3: wxh = H * wx (bf16) ----
#pragma unroll
    for (int mt = 0; mt < 2; mt++)
#pragma unroll
        for (int nt = 0; nt < 2; nt++) { accr[mt][nt] = zz; acci[mt][nt] = zz; }
#pragma unroll
    for (int kk = 0; kk < 8; kk++) {
        bf16x8 hm[2];
#pragma unroll
        for (int mt = 0; mt < 2; mt++) {
            int mtg = w*2 + mt;
            hm[mt] = __builtin_bit_cast(bf16x8, H4[((size_t)kk*16 + mtg)*64 + lane]);
        }
        bf16x8 zr[2], zi_[2];
#pragma unroll
        for (int nt = 0; nt < 2; nt++) {
            int b = nt*16 + lo;
            int du = b*32 + ((kk*4 + hi) ^ (b & 15));
            zr[nt]  = __builtin_bit_cast(bf16x8, lw[0][du]);
            zi_[nt] = __builtin_bit_cast(bf16x8, lw[1][du]);
        }
#pragma unroll
        for (int mt = 0; mt < 2; mt++)
#pragma unroll
            for (int nt = 0; nt < 2; nt++) {
                accr[mt][nt] = __builtin_amdgcn_mfma_f32_16x16x32_bf16(hm[mt], zr[nt],  accr[mt][nt], 0, 0, 0);
                acci[mt][nt] = __builtin_amdgcn_mfma_f32_16x16x32_bf16(hm[mt], zi_[nt], acci[mt][nt], 0, 0, 0);
            }
    }
    // ---- epilogue 3: wxh bf16 planes, [f][b][o] layout ----
#pragma unroll
    for (int mt = 0; mt < 2; mt++)
#pragma unroll
        for (int nt = 0; nt < 2; nt++) {
            int o0 = w*32 + mt*16 + hi*4;
            int b  = nt*16 + lo;
            size_t zb = ((size_t)f*NB + b)*NCH + o0;
            *(uint2*)(wxhR + zb) = make_uint2(pack2(accr[mt][nt][0], accr[mt][nt][1]),
                                              pack2(accr[mt][nt][2], accr[mt][nt][3]));
            *(uint2*)(wxhI + zb) = make_uint2(pack2(acci[mt][nt][0], acci[mt][nt][1]),
                                              pack2(acci[mt][nt][2], acci[mt][nt][3]));
        }
}

// ---------------- pass I: complex ifft along i -> G[j][r][ob] (coalesced stores) ----------------
template<int RH>
__device__ __forceinline__ void ifft_i_body(const unsigned short* __restrict__ YR,
                                            const unsigned short* __restrict__ YI,
                                            float2* __restrict__ G, int j, int ob)
{
    float2 Gacc[16];
#pragma unroll
    for (int rr = 0; rr < 16; rr++) Gacc[rr] = make_float2(0.f, 0.f);
#pragma unroll
    for (int i = 0; i < 32; i++) {
        size_t yi_ = (size_t)(i * 17 + j) * 8192 + ob;
        float Yx = bf2f(YR[yi_]);
        float Yy = bf2f(YI[yi_]);
#pragma unroll
        for (int rr = 0; rr < 16; rr++) {
            int m = (i * (RH * 16 + rr)) & 31;     // compile-time constant
            Gacc[rr].x += Yx*COS32[m] - Yy*SIN32[m];
            Gacc[rr].y += Yx*SIN32[m] + Yy*COS32[m];
        }
    }
#pragma unroll
    for (int rr = 0; rr < 16; rr++) {
        G[((size_t)(j*32 + RH*16 + rr))*8192 + ob] =
            make_float2(Gacc[rr].x * (1.f/32.f), Gacc[rr].y * (1.f/32.f));
    }
}

__global__ __launch_bounds__(256) void ifft_i(const unsigned short* __restrict__ YR,
                                              const unsigned short* __restrict__ YI,
                                              float2* __restrict__ G) {
    int bid = blockIdx.x;
    int j   = bid >> 6;          // 0..16
    int rh  = (bid >> 5) & 1;    // 0..1
    int obc = bid & 31;          // 0..31
    int ob  = obc * 256 + threadIdx.x;
    if (rh == 0) ifft_i_body<0>(YR, YI, G, j, ob);
    else         ifft_i_body<1>(YR, YI, G, j, ob);
}

// ---------------- pass II: irfft along j + bias -> out[b][o][r][s] ----------------
// ob = b*256 + o (plane layout [f][b][o])
__global__ __launch_bounds__(256) void irfft_j(const float2* __restrict__ G,
                                               const float* __restrict__ bias,
                                               float* __restrict__ out) {
    int gid = blockIdx.x * 256 + threadIdx.x;
    int r = gid >> 13, ob = gid & 8191;
    int b = ob >> 8, o = ob & 255;
    float2 Gv[17];
#pragma unroll
    for (int jj = 0; jj < 17; jj++)
        Gv[jj] = G[((size_t)(jj*32 + r))*8192 + ob];
    float y[32];
    float g0 = Gv[0].x, g16 = Gv[16].x;
#pragma unroll
    for (int s = 0; s < 32; s++) y[s] = g0 + ((s & 1) ? -g16 : g16);
#pragma unroll
    for (int jj = 1; jj < 16; jj++) {
#pragma unroll
        for (int s = 0; s < 32; s++) {
            int m = (jj * s) & 31;                 // compile-time constant
            y[s] += 2.f * (Gv[jj].x * COS32[m] - Gv[jj].y * SIN32[m]);
        }
    }
    float bv = bias[o];
    float* op = out + ((size_t)(b * NCH + o) * 32 + r) * 32;
#pragma unroll
    for (int s = 0; s < 32; s++) op[s] = y[s] * (1.f/32.f) + bv;
}

extern "C" void kernel_launch(void* const* d_in, const int* in_sizes, int n_in,
                              void* d_out, int out_size, void* d_ws, size_t ws_size,
                              hipStream_t stream) {
    (void)in_sizes; (void)n_in; (void)out_size;
    if (ws_size < WS_NEED) return;

    const float* x     = (const float*)d_in[0];
    const float* w     = (const float*)d_in[1];
    const float* alpha = (const float*)d_in[2];
    const float* H     = (const float*)d_in[3];
    const float* bias  = (const float*)d_in[4];
    float* out = (float*)d_out;

    char* ws = (char*)d_ws;
    unsigned char* Afrag = (unsigned char*)(ws + OFF_AFRAG);
    float2* tmp = (float2*)(ws + OFF_AFRAG);   // dead before a_build writes Afrag
    float2* G   = (float2*)(ws + OFF_AFRAG);   // live after neum pass (Afrag dead)
    unsigned char* z8r  = (unsigned char*)(ws + OFF_Z8R);
    unsigned char* z8i  = (unsigned char*)(ws + OFF_Z8I);
    float* z32r = (float*)(ws + OFF_Z32R);
    float* z32i = (float*)(ws + OFF_Z32I);
    unsigned short* wxhR = (unsigned short*)(ws + OFF_WXHR);
    unsigned short* wxhI = (unsigned short*)(ws + OFF_WXHI);
    unsigned short* Hfrag = (unsigned short*)(ws + OFF_HFRAG);
    float* red = (float*)(ws + OFF_RED);
    float* sig = red + 256;

    norm_part<<<256, 256, 0, stream>>>(w, red);
    norm_final<<<1, 256, 0, stream>>>(red, alpha, sig);
    hfrag_build<<<dim3(8, 16), 64, 0, stream>>>(H, Hfrag);

    rfft2_reg<<<1024, 256, 0, stream>>>(x, tmp);
    transpose_z<<<dim3(8, 17, 32), 256, 0, stream>>>(tmp, z32r, z32i, z8r, z8i);

    a_build_direct<<<dim3(16, 8, 17), 256, 0, stream>>>(w, sig, (unsigned int*)Afrag);
    neum_fused<<<NF, 512, 0, stream>>>(Afrag, Hfrag, z8r, z8i, z32r, z32i, wxhR, wxhI);

    ifft_i<<<1088, 256, 0, stream>>>(wxhR, wxhI, G);
    irfft_j<<<1024, 256, 0, stream>>>(G, bias, out);
}

// Round 20
// 161.636 us; speedup vs baseline: 1.2723x; 1.0417x over previous
//
#include <hip/hip_runtime.h>
#include <hip/hip_fp8.h>
#include <cstddef>

#define PI_F 3.14159265358979323846f

#define NCH 256   // C
#define NB  32    // B
#define NF  544   // n*(n/2+1),  f = i*17 + j

#define ASCALE     65536.0f
#define INV_ASCALE (1.0f/65536.0f)

typedef short  bf16x8 __attribute__((ext_vector_type(8)));
typedef float  f32x4  __attribute__((ext_vector_type(4)));

// ---- workspace layout (bytes), single-chunk, fp8 A ----
#define SZ_AFRAG ((size_t)NF*8*16*1024)         // 71,303,168 (fp8 fragments; tmp & G alias)
#define SZ_P8    ((size_t)NF*NB*NCH)            // 4,456,448  (fp8 plane)
#define SZ_PB    ((size_t)NF*NB*NCH*2)          // 8,912,896  (bf16 plane)
#define SZ_P32   ((size_t)NF*NB*NCH*4)          // 17,825,792 (fp32 plane)
#define OFF_AFRAG ((size_t)0)
#define OFF_Z8R  (OFF_AFRAG + SZ_AFRAG)
#define OFF_Z8I  (OFF_Z8R + SZ_P8)
#define OFF_Z32R (OFF_Z8I + SZ_P8)
#define OFF_Z32I (OFF_Z32R + SZ_P32)
#define OFF_WXHR (OFF_Z32I + SZ_P32)
#define OFF_WXHI (OFF_WXHR + SZ_PB)
#define OFF_HFRAG (OFF_WXHI + SZ_PB)
#define SZ_HFRAG ((size_t)8*16*1024)            // 131,072
#define OFF_RED  (OFF_HFRAG + SZ_HFRAG)
#define WS_NEED  (OFF_RED + (size_t)4096)       // ~134 MB

// 32-point twiddle tables: COS32[k]=cos(2pi k/32), SIN32[k]=sin(2pi k/32)
__device__ constexpr float COS32[32] = {
     1.0000000000f,  0.9807852804f,  0.9238795325f,  0.8314696123f,
     0.7071067812f,  0.5555702330f,  0.3826834324f,  0.1950903220f,
     0.0000000000f, -0.1950903220f, -0.3826834324f, -0.5555702330f,
    -0.7071067812f, -0.8314696123f, -0.9238795325f, -0.9807852804f,
    -1.0000000000f, -0.9807852804f, -0.9238795325f, -0.8314696123f,
    -0.7071067812f, -0.5555702330f, -0.3826834324f, -0.1950903220f,
    -0.0000000000f,  0.1950903220f,  0.3826834324f,  0.5555702330f,
     0.7071067812f,  0.8314696123f,  0.9238795325f,  0.9807852804f };
__device__ constexpr float SIN32[32] = {
     0.0000000000f,  0.1950903220f,  0.3826834324f,  0.5555702330f,
     0.7071067812f,  0.8314696123f,  0.9238795325f,  0.9807852804f,
     1.0000000000f,  0.9807852804f,  0.9238795325f,  0.8314696123f,
     0.7071067812f,  0.5555702330f,  0.3826834324f,  0.1950903220f,
     0.0000000000f, -0.1950903220f, -0.3826834324f, -0.5555702330f,
    -0.7071067812f, -0.8314696123f, -0.9238795325f, -0.9807852804f,
    -1.0000000000f, -0.9807852804f, -0.9238795325f, -0.8314696123f,
    -0.7071067812f, -0.5555702330f, -0.3826834324f, -0.1950903220f };

__device__ __forceinline__ unsigned short f2bf(float x) {
    unsigned int u = __float_as_uint(x);
    u += 0x7FFFu + ((u >> 16) & 1u);            // RNE
    return (unsigned short)(u >> 16);
}
__device__ __forceinline__ float bf2f(unsigned int h) {
    return __uint_as_float(h << 16);
}
__device__ __forceinline__ unsigned int pack2(float a, float b) {
    return (unsigned int)f2bf(a) | ((unsigned int)f2bf(b) << 16);
}
__device__ __forceinline__ unsigned char f2e4m3(float x) {
    __hip_fp8_e4m3 h(x);
    return (unsigned char)h.__x;
}
__device__ __forceinline__ float e4m3f(unsigned int b) {
    __hip_fp8_e4m3 h; h.__x = (__hip_fp8_storage_t)b;
    return (float)h;
}
__device__ __forceinline__ unsigned int pk4_e4m3(const float* v) {
    return (unsigned)f2e4m3(v[0]) | ((unsigned)f2e4m3(v[1]) << 8) |
           ((unsigned)f2e4m3(v[2]) << 16) | ((unsigned)f2e4m3(v[3]) << 24);
}

// ---------------- norm of wfft (closed form via Parseval) ----------------
__global__ void norm_part(const float* __restrict__ w, float* __restrict__ red) {
    int idx = blockIdx.x * 256 + threadIdx.x;
    const float* wp = w + (size_t)idx * 9;
    float s2 = 0.f, aa = 0.f, bb = 0.f;
#pragma unroll
    for (int u = 0; u < 3; u++) {
        float w0 = wp[u*3+0], w1 = wp[u*3+1], w2 = wp[u*3+2];
        s2 += w0*w0 + w1*w1 + w2*w2;
        float au = w0 + w1 + w2, bu = w0 - w1 + w2;
        aa += au*au; bb += bu*bu;
    }
    float p = 512.f*s2 + 16.f*(aa + bb);
    __shared__ float sm[256];
    sm[threadIdx.x] = p; __syncthreads();
    for (int s = 128; s > 0; s >>= 1) {
        if (threadIdx.x < s) sm[threadIdx.x] += sm[threadIdx.x + s];
        __syncthreads();
    }
    if (threadIdx.x == 0) red[blockIdx.x] = sm[0];
}

__global__ void norm_final(const float* __restrict__ red, const float* __restrict__ alpha,
                           float* __restrict__ sig) {
    __shared__ float sm[256];
    sm[threadIdx.x] = red[threadIdx.x]; __syncthreads();
    for (int s = 128; s > 0; s >>= 1) {
        if (threadIdx.x < s) sm[threadIdx.x] += sm[threadIdx.x + s];
        __syncthreads();
    }
    if (threadIdx.x == 0) sig[0] = alpha[0] / sqrtf(sm[0]);
}

// ---------------- H fragments (A-operand: m=o, k=c), bf16 ----------------
__global__ void hfrag_build(const float* __restrict__ H, unsigned short* __restrict__ Hfrag) {
    int kk = blockIdx.x, mt = blockIdx.y, lane = threadIdx.x;   // 64 threads
    int o = mt*16 + (lane & 15), c0 = kk*32 + (lane >> 4)*8;
    const float* hp = H + (size_t)o*NCH + c0;
    uint4 u;
    u.x = pack2(hp[0], hp[1]); u.y = pack2(hp[2], hp[3]);
    u.z = pack2(hp[4], hp[5]); u.w = pack2(hp[6], hp[7]);
    ((uint4*)Hfrag)[((size_t)kk*16 + mt)*64 + lane] = u;
}

// ---------------- rfft2: register-resident DFT, 8 tiles per 256-thread block ----------------
__global__ __launch_bounds__(256) void rfft2_reg(const float* __restrict__ x,
                                                 float2* __restrict__ tmp)
{
    __shared__ float2 T[8][544];       // [half][r*17+j], ~35 KB
    __shared__ float2 Z[8][544];       // output staging, ~35 KB
    __shared__ float wc[32], wsn[32];
    int t = threadIdx.x;
    int half = t >> 5, lane = t & 31;
    int cb = blockIdx.x * 8 + half;    // tile index in tmp order: cb = c*32 + b
    int c = cb >> 5, b = cb & 31;
    if (t < 32) { wc[t] = COS32[t]; wsn[t] = SIN32[t]; }
    float xr[32];
    const float* xp = x + ((size_t)(b * NCH + c)) * 1024 + lane * 32;
#pragma unroll
    for (int q = 0; q < 8; q++) {
        float4 v = *(const float4*)(xp + q*4);
        xr[q*4+0] = v.x; xr[q*4+1] = v.y; xr[q*4+2] = v.z; xr[q*4+3] = v.w;
    }
    float x0v = xr[0], x16v = xr[16];
    float es[15], os[15];
#pragma unroll
    for (int s = 1; s <= 15; s++) { es[s-1] = xr[s] + xr[32-s]; os[s-1] = xr[s] - xr[32-s]; }
#pragma unroll
    for (int j = 0; j < 17; j++) {
        float ax = x0v + ((j & 1) ? -x16v : x16v);
        float ay = 0.f;
#pragma unroll
        for (int s = 1; s <= 15; s++) {
            int m = (j * s) & 31;
            ax += es[s-1] * COS32[m];
            ay -= os[s-1] * SIN32[m];
        }
        T[half][lane*17 + j] = make_float2(ax, ay);
    }
    __syncthreads();
    float wr_[16], wi_[16];
#pragma unroll
    for (int r = 0; r < 16; r++) {
        int m = (lane * r) & 31;
        wr_[r] = wc[m]; wi_[r] = wsn[m];
    }
    float sgn = (lane & 1) ? -1.f : 1.f;    // (-1)^i
#pragma unroll
    for (int j = 0; j < 17; j++) {
        float ax = 0.f, ay = 0.f;
#pragma unroll
        for (int r = 0; r < 16; r++) {
            float2 t1 = T[half][r*17 + j];
            float2 t2 = T[half][(r+16)*17 + j];
            float ex = fmaf(sgn, t2.x, t1.x);
            float ey = fmaf(sgn, t2.y, t1.y);
            ax += ex * wr_[r] + ey * wi_[r];
            ay += ey * wr_[r] - ex * wi_[r];
        }
        Z[half][lane*17 + j] = make_float2(ax, ay);
    }
    __syncthreads();
    float2* outp = tmp + (size_t)blockIdx.x * 8 * 544;
    const float2* zf = (const float2*)Z;
#pragma unroll
    for (int u = 0; u < 17; u++)
        outp[u*256 + t] = zf[u*256 + t];
}

// ---------------- transpose tmp[cb][f] -> fp32 planes + fp8 planes [f][b][c] ----------------
__global__ __launch_bounds__(256) void transpose_z(const float2* __restrict__ tmp,
        float* __restrict__ z32r, float* __restrict__ z32i,
        unsigned char* __restrict__ z8r, unsigned char* __restrict__ z8i)
{
    __shared__ float2 tile[32][33];
    int ct = blockIdx.x, ft = blockIdx.y, b = blockIdx.z;
    int t = threadIdx.x;
#pragma unroll
    for (int it = 0; it < 4; it++) {
        int idx = t + it*256; int cl = idx >> 5, fl = idx & 31;
        tile[cl][fl] = tmp[((size_t)((ct*32 + cl)*32 + b))*544 + ft*32 + fl];
    }
    __syncthreads();
#pragma unroll
    for (int it = 0; it < 4; it++) {
        int idx = t + it*256; int fl = idx >> 5, cl = idx & 31;
        float2 v = tile[cl][fl];
        size_t zi_ = ((size_t)(ft*32 + fl)*NB + b)*NCH + ct*32 + cl;
        z32r[zi_] = v.x; z32i[zi_] = v.y;
        z8r[zi_] = f2e4m3(v.x); z8i[zi_] = f2e4m3(v.y);
    }
}

// ---------------- A-build, factorized + direct fragment writes ----------------
__global__ __launch_bounds__(256) void a_build_direct(const float* __restrict__ w,
        const float* __restrict__ sig, unsigned int* __restrict__ Afrag)
{
    int mt = blockIdx.x, kk = blockIdx.y, j = blockIdx.z;   // 16, 8, 17
    int t = threadIdx.x;
    int wv = t & 127;
    int c   = mt*16 + ((wv >> 1) & 15);
    int cp0 = kk*32 + (wv >> 5)*8 + (wv & 1)*4;
    bool isReal = (t < 128);
    float sS = sig[0] * ASCALE;
    float sgnS = isReal ? sS : -sS;
    f32x4 P1, P2, P3, P4, P5;
#pragma unroll
    for (int e = 0; e < 4; e++) {
        int cp = cp0 + e;
        const float* p1 = w + ((size_t)c*NCH + cp)*9;
        const float* p2 = w + ((size_t)cp*NCH + c)*9;
        float u_[9];
#pragma unroll
        for (int q = 0; q < 9; q++)
            u_[q] = isReal ? (p1[q] - p2[q]) : (p1[q] + p2[q]);
        if (isReal) {
            P1[e] = sgnS * u_[4];
            P2[e] = sgnS * (u_[3] + u_[5]);
            P3[e] = sgnS * (u_[1] + u_[7]);
            P4[e] = sgnS * (u_[0] + u_[2] + u_[6] + u_[8]);
            P5[e] = sgnS * ((u_[6] - u_[8]) - (u_[0] - u_[2]));
        } else {
            P1[e] = sgnS * (u_[3] - u_[5]);
            P2[e] = sgnS * ((u_[0] - u_[2]) + (u_[6] - u_[8]));
            P3[e] = sgnS * (u_[1] - u_[7]);
            P4[e] = sgnS * ((u_[0] + u_[2]) - (u_[6] + u_[8]));
            P5[e] = 0.f;
        }
    }
    float cps = COS32[j], sns = SIN32[j];
    f32x4 Aj, Bj, Cj;
    if (isReal) { Aj = P1 + cps*P2; Bj = P3 + cps*P4; Cj = sns*P5; }
    else        { Aj = sns*P1;      Bj = sns*P2;      Cj = P3 + cps*P4; }
    unsigned int* out = Afrag + ((size_t)j*128 + kk*16 + mt)*256 + t;
#pragma unroll
    for (int i = 0; i < 32; i++) {
        f32x4 v = Aj + COS32[i]*Bj + SIN32[i]*Cj;   // compile-time twiddles
        *out = (unsigned)f2e4m3(v[0]) | ((unsigned)f2e4m3(v[1]) << 8)
             | ((unsigned)f2e4m3(v[2]) << 16) | ((unsigned)f2e4m3(v[3]) << 24);
        out += (size_t)17*32768;   // fl = i*17 + j
    }
}

// ---------------- neum_fused: t = z - A z ; wx = z32 - 2 A t ; wxh = H wx ----------------
__global__ __launch_bounds__(512) void neum_fused(
    const unsigned char* __restrict__ Afrag,
    const unsigned short* __restrict__ Hfrag,
    const unsigned char* __restrict__ z8r, const unsigned char* __restrict__ z8i,
    const float* __restrict__ z32r, const float* __restrict__ z32i,
    unsigned short* __restrict__ wxhR, unsigned short* __restrict__ wxhI)
{
    __shared__ uint2 lz8[2][1024];   // 16 KB: fp8 z
    __shared__ uint2 lt8[2][1024];   // 16 KB: fp8 t
    __shared__ uint4 lw[2][1024];    // 32 KB: bf16 wx
    int fl = blockIdx.x;
    int f = fl;
    int t = threadIdx.x;
    const uint2* s0 = (const uint2*)(z8r + (size_t)f*8192);
    const uint2* s1 = (const uint2*)(z8i + (size_t)f*8192);
    for (int u = t; u < 2048; u += 512) {
        int p = u >> 10, idx = u & 1023;
        int b = idx >> 5, o16 = idx & 31;
        lz8[p][b*32 + (o16 ^ (b & 15))] = (p ? s1 : s0)[idx];
    }
    int w = t >> 6, lane = t & 63, lo = lane & 15, hi = lane >> 4;
    const uint2* A8 = (const uint2*)Afrag;
    const uint4* H4 = (const uint4*)Hfrag;
    long arK[8][2], aiK[8][2];
#pragma unroll
    for (int kk = 0; kk < 8; kk++) {
#pragma unroll
        for (int mt = 0; mt < 2; mt++) {
            int mtg = w*2 + mt;
            size_t idx = (((size_t)fl*8 + kk)*16 + mtg)*128 + lane;
            arK[kk][mt] = __builtin_bit_cast(long, A8[idx]);
            aiK[kk][mt] = __builtin_bit_cast(long, A8[idx + 64]);
        }
    }
    __syncthreads();   // bar1: mm1 needs staged z
    f32x4 accr[2][2], acci[2][2];
    f32x4 zz = {0.f, 0.f, 0.f, 0.f};
#pragma unroll
    for (int mt = 0; mt < 2; mt++)
#pragma unroll
        for (int nt = 0; nt < 2; nt++) { accr[mt][nt] = zz; acci[mt][nt] = zz; }
    // ---- matmul 1: acc = A * z (fp8) ----
#pragma unroll
    for (int kk = 0; kk < 8; kk++) {
        long zr[2], zi_[2];
#pragma unroll
        for (int nt = 0; nt < 2; nt++) {
            int b = nt*16 + lo;
            int du = b*32 + ((kk*4 + hi) ^ (b & 15));
            zr[nt]  = __builtin_bit_cast(long, lz8[0][du]);
            zi_[nt] = __builtin_bit_cast(long, lz8[1][du]);
        }
#pragma unroll
        for (int mt = 0; mt < 2; mt++) {
            uint2 vb = __builtin_bit_cast(uint2, aiK[kk][mt]);
            long ain = __builtin_bit_cast(long, make_uint2(vb.x ^ 0x80808080u, vb.y ^ 0x80808080u));
#pragma unroll
            for (int nt = 0; nt < 2; nt++) {
                accr[mt][nt] = __builtin_amdgcn_mfma_f32_16x16x32_fp8_fp8(arK[kk][mt], zr[nt],  accr[mt][nt], 0, 0, 0);
                accr[mt][nt] = __builtin_amdgcn_mfma_f32_16x16x32_fp8_fp8(ain,        zi_[nt], accr[mt][nt], 0, 0, 0);
                acci[mt][nt] = __builtin_amdgcn_mfma_f32_16x16x32_fp8_fp8(arK[kk][mt], zi_[nt], acci[mt][nt], 0, 0, 0);
                acci[mt][nt] = __builtin_amdgcn_mfma_f32_16x16x32_fp8_fp8(aiK[kk][mt], zr[nt],  acci[mt][nt], 0, 0, 0);
            }
        }
    }
    // ---- epilogue 1 (no barrier: lz8 read-only here, t goes to lt8) ----
#pragma unroll
    for (int mt = 0; mt < 2; mt++)
#pragma unroll
        for (int nt = 0; nt < 2; nt++) {
            int c0 = w*32 + mt*16 + hi*4;
            int b  = nt*16 + lo;
            int duc = b*32 + ((c0 >> 3) ^ (b & 15));
            int sel = (c0 >> 2) & 1;
            uint2 q0 = lz8[0][duc], q1 = lz8[1][duc];
            unsigned qr = sel ? q0.y : q0.x;
            unsigned qi = sel ? q1.y : q1.x;
            float zfr[4] = { e4m3f(qr & 0xffu), e4m3f((qr>>8)&0xffu),
                             e4m3f((qr>>16)&0xffu), e4m3f(qr>>24) };
            float zfi[4] = { e4m3f(qi & 0xffu), e4m3f((qi>>8)&0xffu),
                             e4m3f((qi>>16)&0xffu), e4m3f(qi>>24) };
            float vr[4], vi[4];
#pragma unroll
            for (int jj = 0; jj < 4; jj++) {
                vr[jj] = zfr[jj] - accr[mt][nt][jj] * INV_ASCALE;
                vi[jj] = zfi[jj] - acci[mt][nt][jj] * INV_ASCALE;
            }
            ((unsigned int*)&lt8[0][duc])[sel] = pk4_e4m3(vr);
            ((unsigned int*)&lt8[1][duc])[sel] = pk4_e4m3(vi);
        }
    __syncthreads();   // bar2: mm2 needs all t writes
    // ---- matmul 2: acc = A * t (A from registers) ----
#pragma unroll
    for (int mt = 0; mt < 2; mt++)
#pragma unroll
        for (int nt = 0; nt < 2; nt++) { accr[mt][nt] = zz; acci[mt][nt] = zz; }
#pragma unroll
    for (int kk = 0; kk < 8; kk++) {
        long zr[2], zi_[2];
#pragma unroll
        for (int nt = 0; nt < 2; nt++) {
            int b = nt*16 + lo;
            int du = b*32 + ((kk*4 + hi) ^ (b & 15));
            zr[nt]  = __builtin_bit_cast(long, lt8[0][du]);
            zi_[nt] = __builtin_bit_cast(long, lt8[1][du]);
        }
#pragma unroll
        for (int mt = 0; mt < 2; mt++) {
            uint2 vb = __builtin_bit_cast(uint2, aiK[kk][mt]);
            long ain = __builtin_bit_cast(long, make_uint2(vb.x ^ 0x80808080u, vb.y ^ 0x80808080u));
#pragma unroll
            for (int nt = 0; nt < 2; nt++) {
                accr[mt][nt] = __builtin_amdgcn_mfma_f32_16x16x32_fp8_fp8(arK[kk][mt], zr[nt],  accr[mt][nt], 0, 0, 0);
                accr[mt][nt] = __builtin_amdgcn_mfma_f32_16x16x32_fp8_fp8(ain,        zi_[nt], accr[mt][nt], 0, 0, 0);
                acci[mt][nt] = __builtin_amdgcn_mfma_f32_16x16x32_fp8_fp8(arK[kk][mt], zi_[nt], acci[mt][nt], 0, 0, 0);
                acci[mt][nt] = __builtin_amdgcn_mfma_f32_16x16x32_fp8_fp8(aiK[kk][mt], zr[nt],  acci[mt][nt], 0, 0, 0);
            }
        }
    }
    // ---- epilogue 2 (no barrier: mm2 reads lt8, we write lw — disjoint) ----
#pragma unroll
    for (int mt = 0; mt < 2; mt++)
#pragma unroll
        for (int nt = 0; nt < 2; nt++) {
            int c0 = w*32 + mt*16 + hi*4;
            int b  = nt*16 + lo;
            size_t zb = ((size_t)f*NB + b)*NCH + c0;
            float4 z4r = *(const float4*)(z32r + zb);
            float4 z4i = *(const float4*)(z32i + zb);
            const float k2 = 2.f * INV_ASCALE;
            float vr[4] = { z4r.x - k2*accr[mt][nt][0], z4r.y - k2*accr[mt][nt][1],
                            z4r.z - k2*accr[mt][nt][2], z4r.w - k2*accr[mt][nt][3] };
            float vi[4] = { z4i.x - k2*acci[mt][nt][0], z4i.y - k2*acci[mt][nt][1],
                            z4i.z - k2*acci[mt][nt][2], z4i.w - k2*acci[mt][nt][3] };
            int o16c = c0 >> 3;
            int duc = b*32 + (o16c ^ (b & 15));
            int sel = (c0 >> 2) & 1;
            ((uint2*)&lw[0][duc])[sel] = make_uint2(pack2(vr[0], vr[1]), pack2(vr[2], vr[3]));
            ((uint2*)&lw[1][duc])[sel] = make_uint2(pack2(vi[0], vi[1]), pack2(vi[2], vi[3]));
        }
    __syncthreads();   // bar3: mm3 needs all wx writes
    // ---- matmul 3: wxh = H * wx (bf16) ----
#pragma unroll
    for (int mt = 0; mt < 2; mt++)
#pragma unroll
        for (int nt = 0; nt < 2; nt++) { accr[mt][nt] = zz; acci[mt][nt] = zz; }
#pragma unroll
    for (int kk = 0; kk < 8; kk++) {
        bf16x8 hm[2];
#pragma unroll
        for (int mt = 0; mt < 2; mt++) {
            int mtg = w*2 + mt;
            hm[mt] = __builtin_bit_cast(bf16x8, H4[((size_t)kk*16 + mtg)*64 + lane]);
        }
        bf16x8 zr[2], zi_[2];
#pragma unroll
        for (int nt = 0; nt < 2; nt++) {
            int b = nt*16 + lo;
            int du = b*32 + ((kk*4 + hi) ^ (b & 15));
            zr[nt]  = __builtin_bit_cast(bf16x8, lw[0][du]);
            zi_[nt] = __builtin_bit_cast(bf16x8, lw[1][du]);
        }
#pragma unroll
        for (int mt = 0; mt < 2; mt++)
#pragma unroll
            for (int nt = 0; nt < 2; nt++) {
                accr[mt][nt] = __builtin_amdgcn_mfma_f32_16x16x32_bf16(hm[mt], zr[nt],  accr[mt][nt], 0, 0, 0);
                acci[mt][nt] = __builtin_amdgcn_mfma_f32_16x16x32_bf16(hm[mt], zi_[nt], acci[mt][nt], 0, 0, 0);
            }
    }
    // ---- epilogue 3: wxh bf16 planes, [f][b][o] layout ----
#pragma unroll
    for (int mt = 0; mt < 2; mt++)
#pragma unroll
        for (int nt = 0; nt < 2; nt++) {
            int o0 = w*32 + mt*16 + hi*4;
            int b  = nt*16 + lo;
            size_t zb = ((size_t)f*NB + b)*NCH + o0;
            *(uint2*)(wxhR + zb) = make_uint2(pack2(accr[mt][nt][0], accr[mt][nt][1]),
                                              pack2(accr[mt][nt][2], accr[mt][nt][3]));
            *(uint2*)(wxhI + zb) = make_uint2(pack2(acci[mt][nt][0], acci[mt][nt][1]),
                                              pack2(acci[mt][nt][2], acci[mt][nt][3]));
        }
}

// ---------------- pass I: complex ifft along i -> G[j][r][ob] packed (bf16 Gr | bf16 Gi) ----------------
template<int RH>
__device__ __forceinline__ void ifft_i_body(const unsigned short* __restrict__ YR,
                                            const unsigned short* __restrict__ YI,
                                            unsigned int* __restrict__ G, int j, int ob)
{
    float2 Gacc[16];
#pragma unroll
    for (int rr = 0; rr < 16; rr++) Gacc[rr] = make_float2(0.f, 0.f);
#pragma unroll
    for (int i = 0; i < 32; i++) {
        size_t yi_ = (size_t)(i * 17 + j) * 8192 + ob;
        float Yx = bf2f(YR[yi_]);
        float Yy = bf2f(YI[yi_]);
#pragma unroll
        for (int rr = 0; rr < 16; rr++) {
            int m = (i * (RH * 16 + rr)) & 31;     // compile-time constant
            Gacc[rr].x += Yx*COS32[m] - Yy*SIN32[m];
            Gacc[rr].y += Yx*SIN32[m] + Yy*COS32[m];
        }
    }
#pragma unroll
    for (int rr = 0; rr < 16; rr++) {
        G[((size_t)(j*32 + RH*16 + rr))*8192 + ob] =
            pack2(Gacc[rr].x * (1.f/32.f), Gacc[rr].y * (1.f/32.f));
    }
}

__global__ __launch_bounds__(256) void ifft_i(const unsigned short* __restrict__ YR,
                                              const unsigned short* __restrict__ YI,
                                              unsigned int* __restrict__ G) {
    int bid = blockIdx.x;
    int j   = bid >> 6;          // 0..16
    int rh  = (bid >> 5) & 1;    // 0..1
    int obc = bid & 31;          // 0..31
    int ob  = obc * 256 + threadIdx.x;
    if (rh == 0) ifft_i_body<0>(YR, YI, G, j, ob);
    else         ifft_i_body<1>(YR, YI, G, j, ob);
}

// ---------------- pass II: irfft along j + bias -> out[b][o][r][s] ----------------
// ob = b*256 + o; G packed (bf16 Gr | bf16 Gi)
__global__ __launch_bounds__(256) void irfft_j(const unsigned int* __restrict__ G,
                                               const float* __restrict__ bias,
                                               float* __restrict__ out) {
    int gid = blockIdx.x * 256 + threadIdx.x;
    int r = gid >> 13, ob = gid & 8191;
    int b = ob >> 8, o = ob & 255;
    float2 Gv[17];
#pragma unroll
    for (int jj = 0; jj < 17; jj++) {
        unsigned p = G[((size_t)(jj*32 + r))*8192 + ob];
        Gv[jj] = make_float2(bf2f(p & 0xffffu), bf2f(p >> 16));
    }
    float y[32];
    float g0 = Gv[0].x, g16 = Gv[16].x;
#pragma unroll
    for (int s = 0; s < 32; s++) y[s] = g0 + ((s & 1) ? -g16 : g16);
#pragma unroll
    for (int jj = 1; jj < 16; jj++) {
#pragma unroll
        for (int s = 0; s < 32; s++) {
            int m = (jj * s) & 31;                 // compile-time constant
            y[s] += 2.f * (Gv[jj].x * COS32[m] - Gv[jj].y * SIN32[m]);
        }
    }
    float bv = bias[o];
    float* op = out + ((size_t)(b * NCH + o) * 32 + r) * 32;
#pragma unroll
    for (int s = 0; s < 32; s++) op[s] = y[s] * (1.f/32.f) + bv;
}

extern "C" void kernel_launch(void* const* d_in, const int* in_sizes, int n_in,
                              void* d_out, int out_size, void* d_ws, size_t ws_size,
                              hipStream_t stream) {
    (void)in_sizes; (void)n_in; (void)out_size;
    if (ws_size < WS_NEED) return;

    const float* x     = (const float*)d_in[0];
    const float* w     = (const float*)d_in[1];
    const float* alpha = (const float*)d_in[2];
    const float* H     = (const float*)d_in[3];
    const float* bias  = (const float*)d_in[4];
    float* out = (float*)d_out;

    char* ws = (char*)d_ws;
    unsigned char* Afrag = (unsigned char*)(ws + OFF_AFRAG);
    float2* tmp = (float2*)(ws + OFF_AFRAG);       // dead before a_build writes Afrag
    unsigned int* G = (unsigned int*)(ws + OFF_AFRAG);  // live after neum pass (Afrag dead)
    unsigned char* z8r  = (unsigned char*)(ws + OFF_Z8R);
    unsigned char* z8i  = (unsigned char*)(ws + OFF_Z8I);
    float* z32r = (float*)(ws + OFF_Z32R);
    float* z32i = (float*)(ws + OFF_Z32I);
    unsigned short* wxhR = (unsigned short*)(ws + OFF_WXHR);
    unsigned short* wxhI = (unsigned short*)(ws + OFF_WXHI);
    unsigned short* Hfrag = (unsigned short*)(ws + OFF_HFRAG);
    float* red = (float*)(ws + OFF_RED);
    float* sig = red + 256;

    norm_part<<<256, 256, 0, stream>>>(w, red);
    norm_final<<<1, 256, 0, stream>>>(red, alpha, sig);
    hfrag_build<<<dim3(8, 16), 64, 0, stream>>>(H, Hfrag);

    rfft2_reg<<<1024, 256, 0, stream>>>(x, tmp);
    transpose_z<<<dim3(8, 17, 32), 256, 0, stream>>>(tmp, z32r, z32i, z8r, z8i);

    a_build_direct<<<dim3(16, 8, 17), 256, 0, stream>>>(w, sig, (unsigned int*)Afrag);
    neum_fused<<<NF, 512, 0, stream>>>(Afrag, Hfrag, z8r, z8i, z32r, z32i, wxhR, wxhI);

    ifft_i<<<1088, 256, 0, stream>>>(wxhR, wxhI, G);
    irfft_j<<<1024, 256, 0, stream>>>(G, bias, out);
}